// Round 16
// baseline (410.709 us; speedup 1.0000x reference)
//
#include <hip/hip_runtime.h>
#include <math.h>

typedef unsigned short u16;
typedef unsigned int u32;
typedef __bf16 bf16x8 __attribute__((ext_vector_type(8)));
typedef float f32x4 __attribute__((ext_vector_type(4)));
typedef u16 u16x4 __attribute__((ext_vector_type(4)));
typedef u16 u16x2 __attribute__((ext_vector_type(2)));

constexpr int B = 8, NQ = 256, LT = 512, NV = 4096;
constexpr int D = 1024, H = 16, DFF = 2048, FTXT = 4096, HD = 64;

__device__ __forceinline__ u16 f2b(float f) {
  u32 u = __builtin_bit_cast(u32, f);
  return (u16)((u + 0x7fffu + ((u >> 16) & 1u)) >> 16);   // RNE
}
__device__ __forceinline__ float b2f(u16 b) {
  u32 u = ((u32)b) << 16;
  return __builtin_bit_cast(float, u);
}
__device__ __forceinline__ void gload16(const void* g, void* l) {
  __builtin_amdgcn_global_load_lds(
      (const __attribute__((address_space(1))) u32*)g,
      (__attribute__((address_space(3))) u32*)l, 16, 0, 0);
}

// ===========================================================================
// Fused text attention: one block per (qhalf, h, b). 512 thr = 8 waves.
// Phase 1: S = Q[128][64] @ K[512][64]^T / 8, mask, softmax (block-wide),
//          out1 += p/H (f32 atomics), P -> bf16 LDS (swizzled).
// Phase 2: ctx = P[128][512] @ vT[64 d][512]^T  (V streamed, 3-slab).
// LDS: P 128K (overlays Q 16K + K 64K) | V 3x8K | red 2K  = ~154 KB.
// ===========================================================================
__global__ __launch_bounds__(512, 1)
void fused_txt_attn(const u16* __restrict__ qb, const u16* __restrict__ kvb,
                    const u16* __restrict__ vT, const int* __restrict__ mask,
                    u16* __restrict__ ctx, float* __restrict__ out1)
{
  __shared__ __align__(16) u16 lds[78848];   // 154 KB
  u16* Qs = lds;                 // [128][64] bf16 @ 0      (16 KB)
  u16* Ks = lds + 8192;          // [512][64] bf16 @ 16 KB  (64 KB)
  u16* Ps = lds;                 // 8 x [128][64] bf16 @ 0  (128 KB, after barrier)
  u16* Vs = lds + 65536;         // 3 x [64][64] bf16       (24 KB)
  float* red = (float*)(lds + 77824);  // [128][4] f32 max | reuse +512 for sum? (2KB)

  const int qhalf = blockIdx.x, h = blockIdx.y, b = blockIdx.z;
  const int t = threadIdx.x;
  const int w = t >> 6, l = t & 63;
  const int l15 = l & 15, l4 = l >> 4, l7 = l & 7;
  const int wr64 = (w >> 2) * 64;        // 2 row-waves (q)
  const int wc128 = (w & 3) * 128;       // 4 col-waves (kv)
  const int q0 = b * NQ + qhalf * 128;   // global q row base

  // ---- stage Q (2 gloads) + K (8 gloads), swizzled ----
  {
    const int srow = t >> 3;
    const int sch = (t & 7) ^ (srow & 7);
    #pragma unroll
    for (int i = 0; i < 2; ++i)
      gload16(&qb[(long long)(q0 + srow + 64 * i) * D + h * HD + sch * 8],
              &Qs[(srow + 64 * i) * 64]);
    #pragma unroll
    for (int i = 0; i < 8; ++i)
      gload16(&kvb[(long long)(b * LT + srow + 64 * i) * 2048 + h * HD + sch * 8],
              &Ks[(srow + 64 * i) * 64]);
  }
  asm volatile("s_waitcnt vmcnt(0)" ::: "memory");
  __syncthreads();

  // ---- S = Q @ K^T ----
  f32x4 acc[4][8];
  {
    bf16x8 a_[4][2], b_[8][2];
    #pragma unroll
    for (int fm = 0; fm < 4; ++fm) {
      const int r = wr64 + fm * 16 + l15;
      a_[fm][0] = *reinterpret_cast<const bf16x8*>(&Qs[r * 64 + (((0 * 4 + l4) ^ (r & 7)) * 8)]);
      a_[fm][1] = *reinterpret_cast<const bf16x8*>(&Qs[r * 64 + (((1 * 4 + l4) ^ (r & 7)) * 8)]);
    }
    #pragma unroll
    for (int fn = 0; fn < 8; ++fn) {
      const int r = wc128 + fn * 16 + l15;
      b_[fn][0] = *reinterpret_cast<const bf16x8*>(&Ks[r * 64 + (((0 * 4 + l4) ^ (r & 7)) * 8)]);
      b_[fn][1] = *reinterpret_cast<const bf16x8*>(&Ks[r * 64 + (((1 * 4 + l4) ^ (r & 7)) * 8)]);
    }
    #pragma unroll
    for (int fm = 0; fm < 4; ++fm)
      #pragma unroll
      for (int fn = 0; fn < 8; ++fn) {
        f32x4 c = {0.f, 0.f, 0.f, 0.f};
        c = __builtin_amdgcn_mfma_f32_16x16x32_bf16(a_[fm][0], b_[fn][0], c, 0, 0, 0);
        c = __builtin_amdgcn_mfma_f32_16x16x32_bf16(a_[fm][1], b_[fn][1], c, 0, 0, 0);
        acc[fm][fn] = c;
      }
  }

  // ---- mask + scale ----
  int mk[8];
  #pragma unroll
  for (int fn = 0; fn < 8; ++fn) mk[fn] = mask[b * LT + wc128 + fn * 16 + l15];
  #pragma unroll
  for (int fm = 0; fm < 4; ++fm)
    #pragma unroll
    for (int fn = 0; fn < 8; ++fn)
      #pragma unroll
      for (int r = 0; r < 4; ++r)
        acc[fm][fn][r] = mk[fn] ? -INFINITY : acc[fm][fn][r] * 0.125f;

  // ---- row max (local fn -> shfl l15 -> cross-wave LDS) ----
  float mx[4][4];
  #pragma unroll
  for (int fm = 0; fm < 4; ++fm)
    #pragma unroll
    for (int r = 0; r < 4; ++r) {
      float m = acc[fm][0][r];
      #pragma unroll
      for (int fn = 1; fn < 8; ++fn) m = fmaxf(m, acc[fm][fn][r]);
      #pragma unroll
      for (int o = 1; o < 16; o <<= 1) m = fmaxf(m, __shfl_xor(m, o, 64));
      mx[fm][r] = m;
    }
  if (l15 == 0) {
    #pragma unroll
    for (int fm = 0; fm < 4; ++fm)
      #pragma unroll
      for (int r = 0; r < 4; ++r)
        red[(wr64 + fm * 16 + l4 * 4 + r) * 4 + (w & 3)] = mx[fm][r];
  }
  __syncthreads();
  #pragma unroll
  for (int fm = 0; fm < 4; ++fm)
    #pragma unroll
    for (int r = 0; r < 4; ++r) {
      const int row = wr64 + fm * 16 + l4 * 4 + r;
      mx[fm][r] = fmaxf(fmaxf(red[row * 4 + 0], red[row * 4 + 1]),
                        fmaxf(red[row * 4 + 2], red[row * 4 + 3]));
    }
  __syncthreads();

  // ---- exp + row sum ----
  float sm[4][4];
  #pragma unroll
  for (int fm = 0; fm < 4; ++fm)
    #pragma unroll
    for (int r = 0; r < 4; ++r) {
      float s = 0.f;
      #pragma unroll
      for (int fn = 0; fn < 8; ++fn) {
        float e = __expf(acc[fm][fn][r] - mx[fm][r]);
        acc[fm][fn][r] = e;
        s += e;
      }
      #pragma unroll
      for (int o = 1; o < 16; o <<= 1) s += __shfl_xor(s, o, 64);
      sm[fm][r] = s;
    }
  if (l15 == 0) {
    #pragma unroll
    for (int fm = 0; fm < 4; ++fm)
      #pragma unroll
      for (int r = 0; r < 4; ++r)
        red[(wr64 + fm * 16 + l4 * 4 + r) * 4 + (w & 3)] = sm[fm][r];
  }
  __syncthreads();
  #pragma unroll
  for (int fm = 0; fm < 4; ++fm)
    #pragma unroll
    for (int r = 0; r < 4; ++r) {
      const int row = wr64 + fm * 16 + l4 * 4 + r;
      sm[fm][r] = 1.f / (red[row * 4 + 0] + red[row * 4 + 1] +
                         red[row * 4 + 2] + red[row * 4 + 3]);
    }
  __syncthreads();   // red done; P region about to be overwritten (Q/K dead)

  // ---- p = e*inv ; out1 atomic ; P -> LDS bf16 (swizzled) ----
  #pragma unroll
  for (int fm = 0; fm < 4; ++fm)
    #pragma unroll
    for (int r = 0; r < 4; ++r) {
      const int row = wr64 + fm * 16 + l4 * 4 + r;
      const long long o1base = ((long long)(q0 + row)) * LT;
      #pragma unroll
      for (int fn = 0; fn < 8; ++fn) {
        const int col = wc128 + fn * 16 + l15;
        const float p = acc[fm][fn][r] * sm[fm][r];
        atomicAdd(&out1[o1base + col], p * (1.f / H));
        const int kt = col >> 6, c6 = col & 63;
        Ps[kt * 8192 + row * 64 + (((c6 >> 3) ^ (row & 7)) * 8) + (c6 & 7)] = f2b(p);
      }
    }
  __syncthreads();

  // ---- PV: ctx[128 q][64 d] = P @ vT^T, V streamed in 8 tiles (3-slab) ----
  auto stV = [&](int slab, int kt) {   // 1 gload: [64 d][64 l]
    const int srow = t >> 3;
    const int sch = (t & 7) ^ (srow & 7);
    gload16(&vT[((long long)b * D + h * HD + srow) * LT + kt * 64 + sch * 8],
            &Vs[slab * 4096 + srow * 64]);
  };
  stV(0, 0); stV(1, 1);
  asm volatile("s_waitcnt vmcnt(1)" ::: "memory");
  __syncthreads();

  f32x4 acc2[4] = {};
  const int pvr = w * 16;   // wave w owns q-rows pvr..pvr+15
  int s0 = 0, s1 = 1, s2 = 2;
  for (int kt = 0; kt < 8; ++kt) {
    bf16x8 pa[2], vb[4][2];
    {
      const int r = pvr + l15;
      pa[0] = *reinterpret_cast<const bf16x8*>(&Ps[kt * 8192 + r * 64 + (((0 * 4 + l4) ^ (r & 7)) * 8)]);
      pa[1] = *reinterpret_cast<const bf16x8*>(&Ps[kt * 8192 + r * 64 + (((1 * 4 + l4) ^ (r & 7)) * 8)]);
      #pragma unroll
      for (int fn = 0; fn < 4; ++fn) {
        const int vr = fn * 16 + l15;
        vb[fn][0] = *reinterpret_cast<const bf16x8*>(&Vs[s0 * 4096 + vr * 64 + (((0 * 4 + l4) ^ (vr & 7)) * 8)]);
        vb[fn][1] = *reinterpret_cast<const bf16x8*>(&Vs[s0 * 4096 + vr * 64 + (((1 * 4 + l4) ^ (vr & 7)) * 8)]);
      }
    }
    if (kt < 6) stV(s2, kt + 2);
    #pragma unroll
    for (int fn = 0; fn < 4; ++fn) {
      acc2[fn] = __builtin_amdgcn_mfma_f32_16x16x32_bf16(pa[0], vb[fn][0], acc2[fn], 0, 0, 0);
      acc2[fn] = __builtin_amdgcn_mfma_f32_16x16x32_bf16(pa[1], vb[fn][1], acc2[fn], 0, 0, 0);
    }
    if (kt < 6)       { asm volatile("s_waitcnt vmcnt(1)" ::: "memory"); }
    else if (kt == 6) { asm volatile("s_waitcnt vmcnt(0)" ::: "memory"); }
    __syncthreads();
    const int tmp = s0; s0 = s1; s1 = s2; s2 = tmp;
  }

  // ---- ctx store ----
  #pragma unroll
  for (int fn = 0; fn < 4; ++fn)
    #pragma unroll
    for (int r = 0; r < 4; ++r) {
      const int row = pvr + l4 * 4 + r;
      ctx[(long long)(q0 + row) * D + h * HD + fn * 16 + l15] = f2b(acc2[fn][r]);
    }
}

// ===========================================================================
// Merged-phase 256x128 schedule (R13/R15-verified).
// ===========================================================================
__global__ __launch_bounds__(512, 2)
void gemm_kv256b(const u16* __restrict__ A, const u16* __restrict__ Bw,
                 const float* __restrict__ bk_, const float* __restrict__ bv_,
                 u16* __restrict__ Cb, u16* __restrict__ vT)
{
  __shared__ __align__(16) u16 As[3 * 16384];
  __shared__ __align__(16) u16 Bs[3 * 8192];

  const int gx = 16;
  const int flat = blockIdx.y * gx + blockIdx.x;
  const int qq = 256 >> 3;
  const int xcd = flat & 7, lid = flat >> 3;
  const int wg = xcd * qq + lid;
  const int bx = wg % gx;
  const int by = wg / gx;
  const int m0 = by * 256, n0 = bx * 128;
  const float* bias = (n0 < 1024) ? (bk_ + n0) : (bv_ + (n0 - 1024));

  const int t = threadIdx.x;
  const int w = t >> 6, l = t & 63;
  const int wr64 = (w >> 1) * 64;
  const int wc64 = (w & 1) * 64;
  const int l15 = l & 15, l4 = l >> 4, l7 = l & 7;

  auto stA = [&](int slab, int tile) {
    const long long kk = (long long)tile * 64 + (((t & 7) ^ ((t >> 3) & 7)) * 8);
    #pragma unroll
    for (int i = 0; i < 4; ++i)
      gload16(&A[(long long)(m0 + (t >> 3) + 64 * i) * 4096 + kk],
              &As[slab * 16384 + (w * 8 + 64 * i) * 64]);
  };
  auto stB = [&](int slab, int tile) {
    const long long kk = (long long)tile * 64 + (((t & 7) ^ ((t >> 3) & 7)) * 8);
    #pragma unroll
    for (int i = 0; i < 2; ++i)
      gload16(&Bw[(long long)(n0 + (t >> 3) + 64 * i) * 4096 + kk],
              &Bs[slab * 8192 + (w * 8 + 64 * i) * 64]);
  };

#define RDA(sl,fm,ks) \
  (*reinterpret_cast<const bf16x8*>(&As[(sl)*16384 + \
      (wr64 + (fm)*16 + l15)*64 + ((((ks)*4 + l4) ^ l7) * 8)]))
#define RDB(sl,fn,ks) \
  (*reinterpret_cast<const bf16x8*>(&Bs[(sl)*8192 + \
      (wc64 + (fn)*16 + l15)*64 + ((((ks)*4 + l4) ^ l7) * 8)]))

  f32x4 acc[4][4] = {};
  bf16x8 a_[4][2];
  bf16x8 b_[4][2];

#define BAR asm volatile("s_barrier" ::: "memory")
#define WAIT6 asm volatile("s_waitcnt vmcnt(6)" ::: "memory")
#define WAIT0 asm volatile("s_waitcnt vmcnt(0)" ::: "memory")

  stA(0, 0); stB(0, 0);
  stA(1, 1); stB(1, 1);
  WAIT6;
  BAR;

  int s0 = 0, s1 = 1, s2 = 2;
  for (int tt = 0; tt < 64; ++tt) {
    #pragma unroll
    for (int f = 0; f < 4; ++f) {
      a_[f][0] = RDA(s0, f, 0); a_[f][1] = RDA(s0, f, 1);
      b_[f][0] = RDB(s0, f, 0); b_[f][1] = RDB(s0, f, 1);
    }

    if (tt < 62) { stA(s2, tt + 2); stB(s2, tt + 2); }

    __builtin_amdgcn_s_setprio(1);
    #pragma unroll
    for (int fm = 0; fm < 4; ++fm)
      #pragma unroll
      for (int fn = 0; fn < 4; ++fn) {
        acc[fm][fn] = __builtin_amdgcn_mfma_f32_16x16x32_bf16(
            a_[fm][0], b_[fn][0], acc[fm][fn], 0, 0, 0);
        acc[fm][fn] = __builtin_amdgcn_mfma_f32_16x16x32_bf16(
            a_[fm][1], b_[fn][1], acc[fm][fn], 0, 0, 0);
      }
    __builtin_amdgcn_s_setprio(0);

    if (tt < 62)       { WAIT6; }
    else if (tt == 62) { WAIT0; }
    BAR;

    const int tmp = s0; s0 = s1; s1 = s2; s2 = tmp;
  }
#undef RDA
#undef RDB
#undef BAR
#undef WAIT6
#undef WAIT0

  if (n0 < 1024) {
    #pragma unroll
    for (int fm = 0; fm < 4; ++fm)
      #pragma unroll
      for (int r = 0; r < 4; ++r) {
        const long long row = m0 + wr64 + fm * 16 + l4 * 4 + r;
        #pragma unroll
        for (int fn = 0; fn < 4; ++fn) {
          const int lc = wc64 + fn * 16 + l15;
          Cb[row * 2048 + n0 + lc] = f2b(acc[fm][fn][r] + bias[lc]);
        }
      }
  } else {
    #pragma unroll
    for (int fm = 0; fm < 4; ++fm) {
      const int row0 = m0 + wr64 + fm * 16 + l4 * 4;
      const int bb = row0 >> 9;
      const int l0 = row0 & 511;
      #pragma unroll
      for (int fn = 0; fn < 4; ++fn) {
        const int lc = wc64 + fn * 16 + l15;
        const int d = n0 + lc - 1024;
        const float bi = bias[lc];
        u16x4 o = {f2b(acc[fm][fn][0] + bi), f2b(acc[fm][fn][1] + bi),
                   f2b(acc[fm][fn][2] + bi), f2b(acc[fm][fn][3] + bi)};
        *reinterpret_cast<u16x4*>(&vT[((long long)bb * D + d) * LT + l0]) = o;
      }
    }
  }
}

template<int NZ2>
__global__ __launch_bounds__(512, 2)
void gemm8(const u16* __restrict__ A, const u16* __restrict__ Bw,
           float* __restrict__ C,
           int Ksub, int lda, int ldb, int ldc, int kstep,
           long long sA1, long long sB1, long long sC1, long long sC2)
{
  __shared__ __align__(16) u16 As[3 * 16384];
  __shared__ __align__(16) u16 Bs[3 * 8192];

  const int gx = gridDim.x, gy = gridDim.y;
  const int nwg = gx * gy * gridDim.z;
  const int flat = (blockIdx.z * gy + blockIdx.y) * gx + blockIdx.x;
  const int qq = nwg >> 3, rr = nwg & 7;
  const int xcd = flat & 7, lid = flat >> 3;
  const int wg = (xcd < rr ? xcd * (qq + 1) : rr * (qq + 1) + (xcd - rr) * qq) + lid;
  const int bx = wg % gx;
  const int tmp1 = wg / gx;
  const int by = tmp1 % gy, bz = tmp1 / gy;
  const int z1 = bz / NZ2, z2 = bz % NZ2;
  const int m0 = by * 256, n0 = bx * 128;
  const long long kbase = (long long)z2 * kstep;
  const u16* Ab = A + (long long)z1 * sA1;
  const u16* Bb = Bw + (long long)z1 * sB1;
  float* Cp = C + (long long)z1 * sC1 + (long long)z2 * sC2;

  const int t = threadIdx.x;
  const int w = t >> 6, l = t & 63;
  const int wr64 = (w >> 1) * 64;
  const int wc64 = (w & 1) * 64;
  const int l15 = l & 15, l4 = l >> 4, l7 = l & 7;

  auto stA = [&](int slab, int tile) {
    const long long kk = kbase + (long long)tile * 64 + (((t & 7) ^ ((t >> 3) & 7)) * 8);
    #pragma unroll
    for (int i = 0; i < 4; ++i)
      gload16(&Ab[(long long)(m0 + (t >> 3) + 64 * i) * lda + kk],
              &As[slab * 16384 + (w * 8 + 64 * i) * 64]);
  };
  auto stB = [&](int slab, int tile) {
    const long long kk = kbase + (long long)tile * 64 + (((t & 7) ^ ((t >> 3) & 7)) * 8);
    #pragma unroll
    for (int i = 0; i < 2; ++i)
      gload16(&Bb[(long long)(n0 + (t >> 3) + 64 * i) * ldb + kk],
              &Bs[slab * 8192 + (w * 8 + 64 * i) * 64]);
  };

#define RDA(sl,fm,ks) \
  (*reinterpret_cast<const bf16x8*>(&As[(sl)*16384 + \
      (wr64 + (fm)*16 + l15)*64 + ((((ks)*4 + l4) ^ l7) * 8)]))
#define RDB(sl,fn,ks) \
  (*reinterpret_cast<const bf16x8*>(&Bs[(sl)*8192 + \
      (wc64 + (fn)*16 + l15)*64 + ((((ks)*4 + l4) ^ l7) * 8)]))

  f32x4 acc[4][4] = {};
  bf16x8 a_[4][2];
  bf16x8 b_[4][2];

#define BAR asm volatile("s_barrier" ::: "memory")
#define WAIT6 asm volatile("s_waitcnt vmcnt(6)" ::: "memory")
#define WAIT0 asm volatile("s_waitcnt vmcnt(0)" ::: "memory")

  stA(0, 0); stB(0, 0);
  stA(1, 1); stB(1, 1);
  WAIT6;
  BAR;

  const int nt = Ksub >> 6;
  int s0 = 0, s1 = 1, s2 = 2;
  for (int tt = 0; tt < nt; ++tt) {
    #pragma unroll
    for (int f = 0; f < 4; ++f) {
      a_[f][0] = RDA(s0, f, 0); a_[f][1] = RDA(s0, f, 1);
      b_[f][0] = RDB(s0, f, 0); b_[f][1] = RDB(s0, f, 1);
    }

    if (tt < nt - 2) { stA(s2, tt + 2); stB(s2, tt + 2); }

    __builtin_amdgcn_s_setprio(1);
    #pragma unroll
    for (int fm = 0; fm < 4; ++fm)
      #pragma unroll
      for (int fn = 0; fn < 4; ++fn) {
        acc[fm][fn] = __builtin_amdgcn_mfma_f32_16x16x32_bf16(
            a_[fm][0], b_[fn][0], acc[fm][fn], 0, 0, 0);
        acc[fm][fn] = __builtin_amdgcn_mfma_f32_16x16x32_bf16(
            a_[fm][1], b_[fn][1], acc[fm][fn], 0, 0, 0);
      }
    __builtin_amdgcn_s_setprio(0);

    if (tt < nt - 2)       { WAIT6; }
    else if (tt == nt - 2) { WAIT0; }
    BAR;

    const int tmp = s0; s0 = s1; s1 = s2; s2 = tmp;
  }
#undef RDA
#undef RDB
#undef BAR
#undef WAIT6
#undef WAIT0

  #pragma unroll
  for (int fm = 0; fm < 4; ++fm)
    #pragma unroll
    for (int r = 0; r < 4; ++r) {
      const long long row = m0 + wr64 + fm * 16 + l4 * 4 + r;
      #pragma unroll
      for (int fn = 0; fn < 4; ++fn) {
        const int lc = wc64 + fn * 16 + l15;
        Cp[row * (long long)ldc + n0 + lc] = acc[fm][fn][r];
      }
    }
}

// ---------------------------------------------------------------------------
// 2-phase bf16 MFMA GEMM (bf16 B via global_load_lds only).
// ---------------------------------------------------------------------------
constexpr int E_BIAS = 1, E_RES = 2, E_RELU = 4, E_WF32 = 8, E_WB16 = 16;

template<int BM, int BN, int WM, int WN, int EPI>
__global__ __launch_bounds__(256)
void gemm_bf16(const u16* __restrict__ A, const u16* __restrict__ Bw,
               const float* __restrict__ bias, const float* __restrict__ res,
               float* __restrict__ C, u16* __restrict__ Cb,
               int K, int lda, int ldb, int ldc, int nbz2,
               long long sA1, long long sA2, long long sB1, long long sB2,
               long long sC1, long long sC2, float alpha)
{
  constexpr int SM = BM / WM, SN = BN / WN;
  constexpr int FM = SM / 16, FN = SN / 16;
  constexpr int PA = BM / 64, PB = BN / 64;
  __shared__ __align__(16) u16 As[2][BM * 32];
  __shared__ __align__(16) u16 Bs[2][BN * 32];

  const int gx = gridDim.x, gy = gridDim.y;
  const int nwg = gx * gy * gridDim.z;
  const int flat = (blockIdx.z * gy + blockIdx.y) * gx + blockIdx.x;
  const int qq = nwg >> 3, rr = nwg & 7;
  const int xcd = flat & 7, lid = flat >> 3;
  const int wg = (xcd < rr ? xcd * (qq + 1) : rr * (qq + 1) + (xcd - rr) * qq) + lid;
  const int bx = wg % gx;
  const int tmp1 = wg / gx;
  const int by = tmp1 % gy, bz = tmp1 / gy;

  const int t = threadIdx.x;
  const int w = t >> 6, l = t & 63;
  const int wr = w / WN, wc = w % WN;
  const int m0 = by * BM, n0 = bx * BN;
  const long long offA = (long long)(bz / nbz2) * sA1 + (long long)(bz % nbz2) * sA2;
  const long long offB = (long long)(bz / nbz2) * sB1 + (long long)(bz % nbz2) * sB2;
  const long long offC = (long long)(bz / nbz2) * sC1 + (long long)(bz % nbz2) * sC2;
  const u16* Ab = A + offA;
  const u16* Bb = Bw + offB;

  const int srow = t >> 2;
  const int sk   = (t & 3) * 8;

  auto stageA = [&](int buf, int k0) {
    #pragma unroll
    for (int p = 0; p < PA; ++p)
      gload16(&Ab[(long long)(m0 + p * 64 + srow) * lda + k0 + sk],
              &As[buf][p * 2048 + w * 512]);
  };
  auto stageB = [&](int buf, int k0) {
    #pragma unroll
    for (int p = 0; p < PB; ++p)
      gload16(&Bb[(long long)(n0 + p * 64 + srow) * ldb + k0 + sk],
              &Bs[buf][p * 2048 + w * 512]);
  };

  f32x4 acc[FM][FN] = {};

  stageA(0, 0);
  stageB(0, 0);

  int cur = 0;
  for (int k0 = 0; k0 < K; k0 += 32) {
    __syncthreads();
    const bool pf = (k0 + 32 < K);
    if (pf) {
      stageA(cur ^ 1, k0 + 32);
      stageB(cur ^ 1, k0 + 32);
    }

    bf16x8 af[FM], bfr[FN];
    #pragma unroll
    for (int i = 0; i < FM; ++i)
      af[i] = *reinterpret_cast<const bf16x8*>(
          &As[cur][(wr * SM + i * 16 + (l & 15)) * 32 + (l >> 4) * 8]);
    #pragma unroll
    for (int j = 0; j < FN; ++j)
      bfr[j] = *reinterpret_cast<const bf16x8*>(
          &Bs[cur][(wc * SN + j * 16 + (l & 15)) * 32 + (l >> 4) * 8]);
    #pragma unroll
    for (int i = 0; i < FM; ++i)
      #pragma unroll
      for (int j = 0; j < FN; ++j)
        acc[i][j] = __builtin_amdgcn_mfma_f32_16x16x32_bf16(af[i], bfr[j], acc[i][j], 0, 0, 0);
    cur ^= 1;
  }

  const int c_l = l & 15, r_l4 = (l >> 4) * 4;
  #pragma unroll
  for (int i = 0; i < FM; ++i) {
    #pragma unroll
    for (int r = 0; r < 4; ++r) {
      const long long row = m0 + wr * SM + i * 16 + r_l4 + r;
      #pragma unroll
      for (int j = 0; j < FN; ++j) {
        const int col = n0 + wc * SN + j * 16 + c_l;
        float v = acc[i][j][r] * alpha;
        if (EPI & E_BIAS) v += bias[col];
        if (EPI & E_RES)  v += res[row * (long long)ldc + col];
        if (EPI & E_RELU) v = fmaxf(v, 0.f);
        const long long co = offC + row * (long long)ldc + col;
        if (EPI & E_WF32) C[co] = v;
        if (EPI & E_WB16) Cb[co] = f2b(v);
      }
    }
  }
}

// ---------------------------------------------------------------------------
__global__ __launch_bounds__(256)
void vox_prep(const float* __restrict__ in, u16* __restrict__ vb,
              u16* __restrict__ vt)
{
  __shared__ u16 tile[64][68];
  const int b = blockIdx.z;
  const int n0 = blockIdx.y * 64;
  const int d0 = blockIdx.x * 64;
  const int t = threadIdx.x;
  const int tr = t >> 4;
  const int tc = (t & 15) * 4;
  const float* ib = in + (long long)b * NV * D;
  u16* vbb = vb + (long long)b * NV * D;
  u16* vtb = vt + (long long)b * NV * D;
  #pragma unroll
  for (int p = 0; p < 4; ++p) {
    int r = tr + p * 16;
    float4 x = *reinterpret_cast<const float4*>(&ib[(long long)(n0 + r) * D + d0 + tc]);
    u16x4 o = {f2b(x.x), f2b(x.y), f2b(x.z), f2b(x.w)};
    *reinterpret_cast<u16x4*>(&vbb[(long long)(n0 + r) * D + d0 + tc]) = o;
    *reinterpret_cast<u16x4*>(&tile[r][tc]) = o;
  }
  __syncthreads();
  #pragma unroll
  for (int p = 0; p < 4; ++p) {
    int c = tr + p * 16;
    u16x4 o = {tile[tc + 0][c], tile[tc + 1][c], tile[tc + 2][c], tile[tc + 3][c]};
    *reinterpret_cast<u16x4*>(&vtb[(long long)(d0 + c) * NV + n0 + tc]) = o;
  }
}

// ---------------------------------------------------------------------------
struct Cvt8 { const float* s[8]; const float* s2[8]; u16* d[8]; int cum[9]; };

__global__ __launch_bounds__(256)
void cvt_multi(Cvt8 a)
{
  const int bidx = blockIdx.x;
  int seg = 0;
  #pragma unroll
  for (int k = 1; k < 8; ++k) if (bidx >= a.cum[k]) seg = k;
  const long long off = ((long long)(bidx - a.cum[seg]) * 256 + threadIdx.x) * 4;
  float4 x = *reinterpret_cast<const float4*>(a.s[seg] + off);
  if (a.s2[seg]) {
    float4 y = *reinterpret_cast<const float4*>(a.s2[seg] + off);
    x.x += y.x; x.y += y.y; x.z += y.z; x.w += y.w;
  }
  u16x4 o = {f2b(x.x), f2b(x.y), f2b(x.z), f2b(x.w)};
  *reinterpret_cast<u16x4*>(a.d[seg] + off) = o;
}

// ---------------------------------------------------------------------------
__global__ __launch_bounds__(256)
void ln_kernel(const float* __restrict__ x, const float* __restrict__ g,
               const float* __restrict__ bia, float* __restrict__ y,
               u16* __restrict__ yb, float scale)
{
  __shared__ float tmp[256];
  const int t = threadIdx.x;
  const long long off = (long long)blockIdx.x * D;
  float4 x4 = *reinterpret_cast<const float4*>(&x[off + t * 4]);
  tmp[t] = x4.x + x4.y + x4.z + x4.w;
  __syncthreads();
  for (int o = 128; o > 0; o >>= 1) { if (t < o) tmp[t] += tmp[t + o]; __syncthreads(); }
  const float mean = tmp[0] * (1.f / D);
  __syncthreads();
  float d0 = x4.x - mean, d1 = x4.y - mean, d2 = x4.z - mean, d3 = x4.w - mean;
  tmp[t] = d0 * d0 + d1 * d1 + d2 * d2 + d3 * d3;
  __syncthreads();
  for (int o = 128; o > 0; o >>= 1) { if (t < o) tmp[t] += tmp[t + o]; __syncthreads(); }
  const float rs = rsqrtf(tmp[0] * (1.f / D) + 1e-5f);
  float4 g4 = *reinterpret_cast<const float4*>(&g[t * 4]);
  float4 b4 = *reinterpret_cast<const float4*>(&bia[t * 4]);
  float o0 = (d0 * rs * g4.x + b4.x) * scale;
  float o1 = (d1 * rs * g4.y + b4.y) * scale;
  float o2 = (d2 * rs * g4.z + b4.z) * scale;
  float o3 = (d3 * rs * g4.w + b4.w) * scale;
  if (y) {
    float4 o4 = {o0, o1, o2, o3};
    *reinterpret_cast<float4*>(&y[off + t * 4]) = o4;
  }
  if (yb) {
    u16x4 ob = {f2b(o0), f2b(o1), f2b(o2), f2b(o3)};
    *reinterpret_cast<u16x4*>(&yb[off + t * 4]) = ob;
  }
}

// ---------------------------------------------------------------------------
__global__ __launch_bounds__(256)
void vox_softmax(float* __restrict__ s, const int* __restrict__ mask,
                 u16* __restrict__ wb)
{
  __shared__ float tmp[256];
  const int t = threadIdx.x;
  const int row = blockIdx.x, b = row / NQ;
  float* sr = s + (long long)row * NV;
  u16* wr = wb + (long long)row * NV;
  const int* mr = mask + b * NV;
  float vals[16];
  float lm = -INFINITY;
  #pragma unroll
  for (int j = 0; j < 16; ++j) {
    int n = t + j * 256;
    float x = mr[n] ? -INFINITY : sr[n];
    vals[j] = x;
    lm = fmaxf(lm, x);
  }
  tmp[t] = lm;
  __syncthreads();
  for (int o = 128; o > 0; o >>= 1) { if (t < o) tmp[t] = fmaxf(tmp[t], tmp[t + o]); __syncthreads(); }
  const float mx = tmp[0];
  __syncthreads();
  float ls = 0.f;
  #pragma unroll
  for (int j = 0; j < 16; ++j) { vals[j] = __expf(vals[j] - mx); ls += vals[j]; }
  tmp[t] = ls;
  __syncthreads();
  for (int o = 128; o > 0; o >>= 1) { if (t < o) tmp[t] += tmp[t + o]; __syncthreads(); }
  const float inv = 1.f / tmp[0];
  #pragma unroll
  for (int j = 0; j < 16; ++j) {
    float v = vals[j] * inv;
    sr[t + j * 256] = v;
    wr[t + j * 256] = f2b(v);
  }
}

__global__ __launch_bounds__(256)
void splitk_reduce(const float* __restrict__ part, float* __restrict__ out)
{
  const long long i = ((long long)blockIdx.x * 256 + threadIdx.x) * 4;
  const long long nd = (long long)NQ * D;
  const long long b = i / nd;
  const long long o = i - b * nd;
  const float* p = part + b * 4 * nd + o;
  float4 s0 = *reinterpret_cast<const float4*>(&p[0]);
  float4 s1 = *reinterpret_cast<const float4*>(&p[nd]);
  float4 s2 = *reinterpret_cast<const float4*>(&p[2 * nd]);
  float4 s3 = *reinterpret_cast<const float4*>(&p[3 * nd]);
  float4 r = {s0.x + s1.x + s2.x + s3.x, s0.y + s1.y + s2.y + s3.y,
              s0.z + s1.z + s2.z + s3.z, s0.w + s1.w + s2.w + s3.w};
  *reinterpret_cast<float4*>(&out[i]) = r;
}

// ---------------------------------------------------------------------------
extern "C" void kernel_launch(void* const* d_in, const int* in_sizes, int n_in,
                              void* d_out, int out_size, void* d_ws, size_t ws_size,
                              hipStream_t stream)
{
  const float* tgt   = (const float*)d_in[0];
  const float* mtxt  = (const float*)d_in[1];
  const float* vox   = (const float*)d_in[2];
  const float* qpos  = (const float*)d_in[3];
  const int*   mtx_m = (const int*)d_in[4];
  const int*   vox_m = (const int*)d_in[5];
  const float* Wq = (const float*)d_in[6];  const float* bq = (const float*)d_in[7];
  const float* Wk = (const float*)d_in[8];  const float* bk = (const float*)d_in[9];
  const float* Wv = (const float*)d_in[10]; const float* bv = (const float*)d_in[11];
  const float* Wo = (const float*)d_in[12]; const float* bo = (const float*)d_in[13];
  const float* W1 = (const float*)d_in[14]; const float* b1 = (const float*)d_in[15];
  const float* W2 = (const float*)d_in[16]; const float* b2 = (const float*)d_in[17];
  const float* ln1g = (const float*)d_in[18]; const float* ln1b = (const float*)d_in[19];
  const float* ln2g = (const float*)d_in[20]; const float* ln2b = (const float*)d_in[21];

  float* out0 = (float*)d_out;                       // attn_output  [B,NQ,D]
  float* out1 = out0 + (long long)B * NQ * D;        // txt_cross    [B,NQ,LT]
  float* out2 = out1 + (long long)B * NQ * LT;       // attn_weights [B,NQ,NV]

  char* base = (char*)d_ws;
  constexpr size_t MB = 1ull << 20;
  u16*   kvW   = (u16*)(base + 0 * MB);     // 16  [Wk;Wv] stacked
  u16*   Wq_b  = (u16*)(base + 16 * MB);    // 2
  u16*   Wo_b  = (u16*)(base + 18 * MB);    // 2
  u16*   W1_b  = (u16*)(base + 20 * MB);    // 4
  u16*   W2_b  = (u16*)(base + 24 * MB);    // 4
  u16*   tq_b  = (u16*)(base + 28 * MB);    // 4
  u16*   q_b   = (u16*)(base + 32 * MB);    // 4
  u16*   kv_b  = (u16*)(base + 36 * MB);    // 16  [B*LT][2048] (K half used)
  u16*   vT_b  = (u16*)(base + 52 * MB);    // 8   [B][D][LT]
  u16*   ctx_b = (u16*)(base + 60 * MB);    // 4
  float* x1p   = (float*)(base + 64 * MB);  // 8
  float* x1f   = (float*)(base + 72 * MB);  // 8
  u16*   x1_b  = (u16*)(base + 80 * MB);    // 4
  u16*   ff1_b = (u16*)(base + 84 * MB);    // 8
  float* x2p   = (float*)(base + 92 * MB);  // 8
  u16*   x2s_b = (u16*)(base + 100 * MB);   // 4
  u16*   mtxt_b = (u16*)(base + 104 * MB);  // 32  dead after kv256b
  u16*   vox_b  = (u16*)(base + 104 * MB);  // 64  overlays mtxt_b (dead)
  u16*   voxT_b = (u16*)(base + 168 * MB);  // 64
  u16*   wvox_b = (u16*)(base + 0 * MB);    // 16  overlays kvW (dead)
  float* part   = (float*)(base + 16 * MB); // 32  overlays Wq..q_b (dead)

  const dim3 blk(256);
  const long long nd = (long long)NQ * D;

  // 1) conversions: fused weights + memory_txt + (tgt+qpos)
  Cvt8 ca;
  for (int i = 0; i < 8; ++i) ca.s2[i] = nullptr;
  ca.s[0] = Wq;   ca.d[0] = Wq_b;
  ca.s[1] = Wk;   ca.d[1] = kvW;
  ca.s[2] = Wv;   ca.d[2] = kvW + (long long)D * FTXT;
  ca.s[3] = Wo;   ca.d[3] = Wo_b;
  ca.s[4] = W1;   ca.d[4] = W1_b;
  ca.s[5] = W2;   ca.d[5] = W2_b;
  ca.s[6] = mtxt; ca.d[6] = mtxt_b;
  ca.s[7] = tgt;  ca.s2[7] = qpos; ca.d[7] = tq_b;
  ca.cum[0] = 0;     ca.cum[1] = 1024;  ca.cum[2] = 5120;  ca.cum[3] = 9216;
  ca.cum[4] = 10240; ca.cum[5] = 12288; ca.cum[6] = 14336; ca.cum[7] = 30720;
  ca.cum[8] = 32768;
  cvt_multi<<<dim3(32768), blk, 0, stream>>>(ca);

  // 2) q projection (2-phase) + kv projection (merged-phase; V -> vT fused)
  gemm_bf16<64,64,2,2, E_BIAS|E_WB16><<<dim3(D/64, (B*NQ)/64, 1), blk, 0, stream>>>(
      tq_b, Wq_b, bq, nullptr, nullptr, q_b, D, D, D, D, 1, 0,0,0,0,0,0, 1.f);
  gemm_kv256b<<<dim3(16, 16), dim3(512), 0, stream>>>(mtxt_b, kvW, bk, bv, kv_b, vT_b);

  // 3) fused text attention (scores + softmax + head-mean + P@V)
  hipMemsetAsync(out1, 0, (long long)B * NQ * LT * sizeof(float), stream);
  fused_txt_attn<<<dim3(2, H, B), dim3(512), 0, stream>>>(
      q_b, kv_b, vT_b, mtx_m, ctx_b, out1);

  // 4) vox -> vox_b + voxT_b (one f32 read)
  vox_prep<<<dim3(D/64, NV/64, B), blk, 0, stream>>>(vox, vox_b, voxT_b);

  // 5) x1p = tgt + ctx @ Wo^T + bo
  gemm_bf16<64,64,2,2, E_BIAS|E_RES|E_WF32><<<dim3(D/64, (B*NQ)/64, 1), blk, 0, stream>>>(
      ctx_b, Wo_b, bo, tgt, x1p, nullptr, D, D, D, D, 1, 0,0,0,0,0,0, 1.f);

  // 6) LN1
  ln_kernel<<<dim3(B*NQ), blk, 0, stream>>>(x1p, ln1g, ln1b, x1f, x1_b, 1.f);

  // 7) ff1 = relu(x1 @ W1^T + b1)
  gemm_bf16<128,64,2,2, E_BIAS|E_RELU|E_WB16><<<dim3(DFF/64, (B*NQ)/128, 1), blk, 0, stream>>>(
      x1_b, W1_b, b1, nullptr, nullptr, ff1_b, D, D, D, DFF, 1, 0,0,0,0,0,0, 1.f);

  // 8) x2p = x1 + ff1 @ W2^T + b2
  gemm_bf16<64,64,2,2, E_BIAS|E_RES|E_WF32><<<dim3(D/64, (B*NQ)/64, 1), blk, 0, stream>>>(
      ff1_b, W2_b, b2, x1f, x2p, nullptr, DFF, DFF, DFF, D, 1, 0,0,0,0,0,0, 1.f);

  // 9) LN2 -> x2s (bf16, /sqrt(D))
  ln_kernel<<<dim3(B*NQ), blk, 0, stream>>>(x2p, ln2g, ln2b, nullptr, x2s_b, 0.03125f);

  // 10) out2 = x2s @ vox_b^T  (merged-phase)
  gemm8<1><<<dim3(NV/128, 1, B), dim3(512), 0, stream>>>(
      x2s_b, vox_b, out2, D, D, D, NV, 0,
      nd, (long long)NV * D, (long long)NQ * NV, 0);

  // 11) masked softmax in place; bf16 weights
  vox_softmax<<<dim3(B*NQ), blk, 0, stream>>>(out2, vox_m, wvox_b);

  // 12) out0 partials: merged-phase split-K=4 + reduce
  gemm8<4><<<dim3(D/128, 1, B*4), dim3(512), 0, stream>>>(
      wvox_b, voxT_b, part, NV/4, NV, NV, D, NV/4,
      (long long)NQ * NV, (long long)D * NV, 4 * nd, nd);
  splitk_reduce<<<dim3((B * NQ * D) / 1024), blk, 0, stream>>>(part, out0);
}

// Round 17
// 410.376 us; speedup vs baseline: 1.0008x; 1.0008x over previous
//
#include <hip/hip_runtime.h>
#include <math.h>

typedef unsigned short u16;
typedef unsigned int u32;
typedef __bf16 bf16x8 __attribute__((ext_vector_type(8)));
typedef float f32x4 __attribute__((ext_vector_type(4)));
typedef u16 u16x4 __attribute__((ext_vector_type(4)));
typedef u16 u16x2 __attribute__((ext_vector_type(2)));

constexpr int B = 8, NQ = 256, LT = 512, NV = 4096;
constexpr int D = 1024, H = 16, DFF = 2048, FTXT = 4096, HD = 64;

__device__ __forceinline__ u16 f2b(float f) {
  u32 u = __builtin_bit_cast(u32, f);
  return (u16)((u + 0x7fffu + ((u >> 16) & 1u)) >> 16);   // RNE
}
__device__ __forceinline__ float b2f(u16 b) {
  u32 u = ((u32)b) << 16;
  return __builtin_bit_cast(float, u);
}
__device__ __forceinline__ void gload16(const void* g, void* l) {
  __builtin_amdgcn_global_load_lds(
      (const __attribute__((address_space(1))) u32*)g,
      (__attribute__((address_space(3))) u32*)l, 16, 0, 0);
}

// fast zero for out1 (hipMemsetAsync's fill kernel runs at ~55 GB/s on 4 MB)
__global__ __launch_bounds__(256)
void zero_out1(float* __restrict__ p)
{
  const long long i = ((long long)blockIdx.x * 256 + threadIdx.x) * 4;
  float4 z = {0.f, 0.f, 0.f, 0.f};
  *reinterpret_cast<float4*>(&p[i]) = z;
}

// ===========================================================================
// Fused text attention (R16-verified numerics): one block per (qhalf, h, b).
// ===========================================================================
__global__ __launch_bounds__(512, 1)
void fused_txt_attn(const u16* __restrict__ qb, const u16* __restrict__ kvb,
                    const u16* __restrict__ vT, const int* __restrict__ mask,
                    u16* __restrict__ ctx, float* __restrict__ out1)
{
  __shared__ __align__(16) u16 lds[78848];   // 154 KB
  u16* Qs = lds;                 // [128][64] bf16 @ 0      (16 KB)
  u16* Ks = lds + 8192;          // [512][64] bf16 @ 16 KB  (64 KB)
  u16* Ps = lds;                 // 8 x [128][64] bf16 @ 0  (128 KB, after barrier)
  u16* Vs = lds + 65536;         // 3 x [64][64] bf16       (24 KB)
  float* red = (float*)(lds + 77824);  // [128][4] f32 (2 KB)

  const int qhalf = blockIdx.x, h = blockIdx.y, b = blockIdx.z;
  const int t = threadIdx.x;
  const int w = t >> 6, l = t & 63;
  const int l15 = l & 15, l4 = l >> 4;
  const int wr64 = (w >> 2) * 64;        // 2 row-waves (q)
  const int wc128 = (w & 3) * 128;       // 4 col-waves (kv)
  const int q0 = b * NQ + qhalf * 128;   // global q row base

  // ---- stage Q (2 gloads) + K (8 gloads), swizzled ----
  {
    const int srow = t >> 3;
    const int sch = (t & 7) ^ (srow & 7);
    #pragma unroll
    for (int i = 0; i < 2; ++i)
      gload16(&qb[(long long)(q0 + srow + 64 * i) * D + h * HD + sch * 8],
              &Qs[(srow + 64 * i) * 64]);
    #pragma unroll
    for (int i = 0; i < 8; ++i)
      gload16(&kvb[(long long)(b * LT + srow + 64 * i) * 2048 + h * HD + sch * 8],
              &Ks[(srow + 64 * i) * 64]);
  }
  asm volatile("s_waitcnt vmcnt(0)" ::: "memory");
  __syncthreads();

  // ---- S = Q @ K^T ----
  f32x4 acc[4][8];
  {
    bf16x8 a_[4][2], b_[8][2];
    #pragma unroll
    for (int fm = 0; fm < 4; ++fm) {
      const int r = wr64 + fm * 16 + l15;
      a_[fm][0] = *reinterpret_cast<const bf16x8*>(&Qs[r * 64 + (((0 * 4 + l4) ^ (r & 7)) * 8)]);
      a_[fm][1] = *reinterpret_cast<const bf16x8*>(&Qs[r * 64 + (((1 * 4 + l4) ^ (r & 7)) * 8)]);
    }
    #pragma unroll
    for (int fn = 0; fn < 8; ++fn) {
      const int r = wc128 + fn * 16 + l15;
      b_[fn][0] = *reinterpret_cast<const bf16x8*>(&Ks[r * 64 + (((0 * 4 + l4) ^ (r & 7)) * 8)]);
      b_[fn][1] = *reinterpret_cast<const bf16x8*>(&Ks[r * 64 + (((1 * 4 + l4) ^ (r & 7)) * 8)]);
    }
    #pragma unroll
    for (int fm = 0; fm < 4; ++fm)
      #pragma unroll
      for (int fn = 0; fn < 8; ++fn) {
        f32x4 c = {0.f, 0.f, 0.f, 0.f};
        c = __builtin_amdgcn_mfma_f32_16x16x32_bf16(a_[fm][0], b_[fn][0], c, 0, 0, 0);
        c = __builtin_amdgcn_mfma_f32_16x16x32_bf16(a_[fm][1], b_[fn][1], c, 0, 0, 0);
        acc[fm][fn] = c;
      }
  }

  // ---- mask + scale ----
  int mk[8];
  #pragma unroll
  for (int fn = 0; fn < 8; ++fn) mk[fn] = mask[b * LT + wc128 + fn * 16 + l15];
  #pragma unroll
  for (int fm = 0; fm < 4; ++fm)
    #pragma unroll
    for (int fn = 0; fn < 8; ++fn)
      #pragma unroll
      for (int r = 0; r < 4; ++r)
        acc[fm][fn][r] = mk[fn] ? -INFINITY : acc[fm][fn][r] * 0.125f;

  // ---- row max ----
  float mx[4][4];
  #pragma unroll
  for (int fm = 0; fm < 4; ++fm)
    #pragma unroll
    for (int r = 0; r < 4; ++r) {
      float m = acc[fm][0][r];
      #pragma unroll
      for (int fn = 1; fn < 8; ++fn) m = fmaxf(m, acc[fm][fn][r]);
      #pragma unroll
      for (int o = 1; o < 16; o <<= 1) m = fmaxf(m, __shfl_xor(m, o, 64));
      mx[fm][r] = m;
    }
  if (l15 == 0) {
    #pragma unroll
    for (int fm = 0; fm < 4; ++fm)
      #pragma unroll
      for (int r = 0; r < 4; ++r)
        red[(wr64 + fm * 16 + l4 * 4 + r) * 4 + (w & 3)] = mx[fm][r];
  }
  __syncthreads();
  #pragma unroll
  for (int fm = 0; fm < 4; ++fm)
    #pragma unroll
    for (int r = 0; r < 4; ++r) {
      const int row = wr64 + fm * 16 + l4 * 4 + r;
      mx[fm][r] = fmaxf(fmaxf(red[row * 4 + 0], red[row * 4 + 1]),
                        fmaxf(red[row * 4 + 2], red[row * 4 + 3]));
    }
  __syncthreads();

  // ---- exp + row sum ----
  float sm[4][4];
  #pragma unroll
  for (int fm = 0; fm < 4; ++fm)
    #pragma unroll
    for (int r = 0; r < 4; ++r) {
      float s = 0.f;
      #pragma unroll
      for (int fn = 0; fn < 8; ++fn) {
        float e = __expf(acc[fm][fn][r] - mx[fm][r]);
        acc[fm][fn][r] = e;
        s += e;
      }
      #pragma unroll
      for (int o = 1; o < 16; o <<= 1) s += __shfl_xor(s, o, 64);
      sm[fm][r] = s;
    }
  if (l15 == 0) {
    #pragma unroll
    for (int fm = 0; fm < 4; ++fm)
      #pragma unroll
      for (int r = 0; r < 4; ++r)
        red[(wr64 + fm * 16 + l4 * 4 + r) * 4 + (w & 3)] = sm[fm][r];
  }
  __syncthreads();
  #pragma unroll
  for (int fm = 0; fm < 4; ++fm)
    #pragma unroll
    for (int r = 0; r < 4; ++r) {
      const int row = wr64 + fm * 16 + l4 * 4 + r;
      sm[fm][r] = 1.f / (red[row * 4 + 0] + red[row * 4 + 1] +
                         red[row * 4 + 2] + red[row * 4 + 3]);
    }
  __syncthreads();

  // ---- p = e*inv ; out1 atomic ; P -> LDS bf16 (swizzled) ----
  #pragma unroll
  for (int fm = 0; fm < 4; ++fm)
    #pragma unroll
    for (int r = 0; r < 4; ++r) {
      const int row = wr64 + fm * 16 + l4 * 4 + r;
      const long long o1base = ((long long)(q0 + row)) * LT;
      #pragma unroll
      for (int fn = 0; fn < 8; ++fn) {
        const int col = wc128 + fn * 16 + l15;
        const float p = acc[fm][fn][r] * sm[fm][r];
        atomicAdd(&out1[o1base + col], p * (1.f / H));
        const int kt = col >> 6, c6 = col & 63;
        Ps[kt * 8192 + row * 64 + (((c6 >> 3) ^ (row & 7)) * 8) + (c6 & 7)] = f2b(p);
      }
    }
  __syncthreads();

  // ---- PV: ctx = P @ vT^T, V streamed in 8 tiles (3-slab) ----
  auto stV = [&](int slab, int kt) {
    const int srow = t >> 3;
    const int sch = (t & 7) ^ (srow & 7);
    gload16(&vT[((long long)b * D + h * HD + srow) * LT + kt * 64 + sch * 8],
            &Vs[slab * 4096 + srow * 64]);
  };
  stV(0, 0); stV(1, 1);
  asm volatile("s_waitcnt vmcnt(1)" ::: "memory");
  __syncthreads();

  f32x4 acc2[4] = {};
  const int pvr = w * 16;
  int s0 = 0, s1 = 1, s2 = 2;
  for (int kt = 0; kt < 8; ++kt) {
    bf16x8 pa[2], vb[4][2];
    {
      const int r = pvr + l15;
      pa[0] = *reinterpret_cast<const bf16x8*>(&Ps[kt * 8192 + r * 64 + (((0 * 4 + l4) ^ (r & 7)) * 8)]);
      pa[1] = *reinterpret_cast<const bf16x8*>(&Ps[kt * 8192 + r * 64 + (((1 * 4 + l4) ^ (r & 7)) * 8)]);
      #pragma unroll
      for (int fn = 0; fn < 4; ++fn) {
        const int vr = fn * 16 + l15;
        vb[fn][0] = *reinterpret_cast<const bf16x8*>(&Vs[s0 * 4096 + vr * 64 + (((0 * 4 + l4) ^ (vr & 7)) * 8)]);
        vb[fn][1] = *reinterpret_cast<const bf16x8*>(&Vs[s0 * 4096 + vr * 64 + (((1 * 4 + l4) ^ (vr & 7)) * 8)]);
      }
    }
    if (kt < 6) stV(s2, kt + 2);
    #pragma unroll
    for (int fn = 0; fn < 4; ++fn) {
      acc2[fn] = __builtin_amdgcn_mfma_f32_16x16x32_bf16(pa[0], vb[fn][0], acc2[fn], 0, 0, 0);
      acc2[fn] = __builtin_amdgcn_mfma_f32_16x16x32_bf16(pa[1], vb[fn][1], acc2[fn], 0, 0, 0);
    }
    if (kt < 6)       { asm volatile("s_waitcnt vmcnt(1)" ::: "memory"); }
    else if (kt == 6) { asm volatile("s_waitcnt vmcnt(0)" ::: "memory"); }
    __syncthreads();
    const int tmp = s0; s0 = s1; s1 = s2; s2 = tmp;
  }

  #pragma unroll
  for (int fn = 0; fn < 4; ++fn)
    #pragma unroll
    for (int r = 0; r < 4; ++r) {
      const int row = pvr + l4 * 4 + r;
      ctx[(long long)(q0 + row) * D + h * HD + fn * 16 + l15] = f2b(acc2[fn][r]);
    }
}

// ===========================================================================
// Merged-phase 256x128 schedule (R13/R15-verified).
// ===========================================================================
__global__ __launch_bounds__(512, 2)
void gemm_kv256b(const u16* __restrict__ A, const u16* __restrict__ Bw,
                 const float* __restrict__ bk_, const float* __restrict__ bv_,
                 u16* __restrict__ Cb, u16* __restrict__ vT)
{
  __shared__ __align__(16) u16 As[3 * 16384];
  __shared__ __align__(16) u16 Bs[3 * 8192];

  const int gx = 16;
  const int flat = blockIdx.y * gx + blockIdx.x;
  const int qq = 256 >> 3;
  const int xcd = flat & 7, lid = flat >> 3;
  const int wg = xcd * qq + lid;
  const int bx = wg % gx;
  const int by = wg / gx;
  const int m0 = by * 256, n0 = bx * 128;
  const float* bias = (n0 < 1024) ? (bk_ + n0) : (bv_ + (n0 - 1024));

  const int t = threadIdx.x;
  const int w = t >> 6, l = t & 63;
  const int wr64 = (w >> 1) * 64;
  const int wc64 = (w & 1) * 64;
  const int l15 = l & 15, l4 = l >> 4, l7 = l & 7;

  auto stA = [&](int slab, int tile) {
    const long long kk = (long long)tile * 64 + (((t & 7) ^ ((t >> 3) & 7)) * 8);
    #pragma unroll
    for (int i = 0; i < 4; ++i)
      gload16(&A[(long long)(m0 + (t >> 3) + 64 * i) * 4096 + kk],
              &As[slab * 16384 + (w * 8 + 64 * i) * 64]);
  };
  auto stB = [&](int slab, int tile) {
    const long long kk = (long long)tile * 64 + (((t & 7) ^ ((t >> 3) & 7)) * 8);
    #pragma unroll
    for (int i = 0; i < 2; ++i)
      gload16(&Bw[(long long)(n0 + (t >> 3) + 64 * i) * 4096 + kk],
              &Bs[slab * 8192 + (w * 8 + 64 * i) * 64]);
  };

#define RDA(sl,fm,ks) \
  (*reinterpret_cast<const bf16x8*>(&As[(sl)*16384 + \
      (wr64 + (fm)*16 + l15)*64 + ((((ks)*4 + l4) ^ l7) * 8)]))
#define RDB(sl,fn,ks) \
  (*reinterpret_cast<const bf16x8*>(&Bs[(sl)*8192 + \
      (wc64 + (fn)*16 + l15)*64 + ((((ks)*4 + l4) ^ l7) * 8)]))

  f32x4 acc[4][4] = {};
  bf16x8 a_[4][2];
  bf16x8 b_[4][2];

#define BAR asm volatile("s_barrier" ::: "memory")
#define WAIT6 asm volatile("s_waitcnt vmcnt(6)" ::: "memory")
#define WAIT0 asm volatile("s_waitcnt vmcnt(0)" ::: "memory")

  stA(0, 0); stB(0, 0);
  stA(1, 1); stB(1, 1);
  WAIT6;
  BAR;

  int s0 = 0, s1 = 1, s2 = 2;
  for (int tt = 0; tt < 64; ++tt) {
    #pragma unroll
    for (int f = 0; f < 4; ++f) {
      a_[f][0] = RDA(s0, f, 0); a_[f][1] = RDA(s0, f, 1);
      b_[f][0] = RDB(s0, f, 0); b_[f][1] = RDB(s0, f, 1);
    }

    if (tt < 62) { stA(s2, tt + 2); stB(s2, tt + 2); }

    __builtin_amdgcn_s_setprio(1);
    #pragma unroll
    for (int fm = 0; fm < 4; ++fm)
      #pragma unroll
      for (int fn = 0; fn < 4; ++fn) {
        acc[fm][fn] = __builtin_amdgcn_mfma_f32_16x16x32_bf16(
            a_[fm][0], b_[fn][0], acc[fm][fn], 0, 0, 0);
        acc[fm][fn] = __builtin_amdgcn_mfma_f32_16x16x32_bf16(
            a_[fm][1], b_[fn][1], acc[fm][fn], 0, 0, 0);
      }
    __builtin_amdgcn_s_setprio(0);

    if (tt < 62)       { WAIT6; }
    else if (tt == 62) { WAIT0; }
    BAR;

    const int tmp = s0; s0 = s1; s1 = s2; s2 = tmp;
  }
#undef RDA
#undef RDB
#undef BAR
#undef WAIT6
#undef WAIT0

  if (n0 < 1024) {
    #pragma unroll
    for (int fm = 0; fm < 4; ++fm)
      #pragma unroll
      for (int r = 0; r < 4; ++r) {
        const long long row = m0 + wr64 + fm * 16 + l4 * 4 + r;
        #pragma unroll
        for (int fn = 0; fn < 4; ++fn) {
          const int lc = wc64 + fn * 16 + l15;
          Cb[row * 2048 + n0 + lc] = f2b(acc[fm][fn][r] + bias[lc]);
        }
      }
  } else {
    #pragma unroll
    for (int fm = 0; fm < 4; ++fm) {
      const int row0 = m0 + wr64 + fm * 16 + l4 * 4;
      const int bb = row0 >> 9;
      const int l0 = row0 & 511;
      #pragma unroll
      for (int fn = 0; fn < 4; ++fn) {
        const int lc = wc64 + fn * 16 + l15;
        const int d = n0 + lc - 1024;
        const float bi = bias[lc];
        u16x4 o = {f2b(acc[fm][fn][0] + bi), f2b(acc[fm][fn][1] + bi),
                   f2b(acc[fm][fn][2] + bi), f2b(acc[fm][fn][3] + bi)};
        *reinterpret_cast<u16x4*>(&vT[((long long)bb * D + d) * LT + l0]) = o;
      }
    }
  }
}

template<int NZ2>
__global__ __launch_bounds__(512, 2)
void gemm8(const u16* __restrict__ A, const u16* __restrict__ Bw,
           float* __restrict__ C,
           int Ksub, int lda, int ldb, int ldc, int kstep,
           long long sA1, long long sB1, long long sC1, long long sC2)
{
  __shared__ __align__(16) u16 As[3 * 16384];
  __shared__ __align__(16) u16 Bs[3 * 8192];

  const int gx = gridDim.x, gy = gridDim.y;
  const int nwg = gx * gy * gridDim.z;
  const int flat = (blockIdx.z * gy + blockIdx.y) * gx + blockIdx.x;
  const int qq = nwg >> 3, rr = nwg & 7;
  const int xcd = flat & 7, lid = flat >> 3;
  const int wg = (xcd < rr ? xcd * (qq + 1) : rr * (qq + 1) + (xcd - rr) * qq) + lid;
  const int bx = wg % gx;
  const int tmp1 = wg / gx;
  const int by = tmp1 % gy, bz = tmp1 / gy;
  const int z1 = bz / NZ2, z2 = bz % NZ2;
  const int m0 = by * 256, n0 = bx * 128;
  const long long kbase = (long long)z2 * kstep;
  const u16* Ab = A + (long long)z1 * sA1;
  const u16* Bb = Bw + (long long)z1 * sB1;
  float* Cp = C + (long long)z1 * sC1 + (long long)z2 * sC2;

  const int t = threadIdx.x;
  const int w = t >> 6, l = t & 63;
  const int wr64 = (w >> 1) * 64;
  const int wc64 = (w & 1) * 64;
  const int l15 = l & 15, l4 = l >> 4, l7 = l & 7;

  auto stA = [&](int slab, int tile) {
    const long long kk = kbase + (long long)tile * 64 + (((t & 7) ^ ((t >> 3) & 7)) * 8);
    #pragma unroll
    for (int i = 0; i < 4; ++i)
      gload16(&Ab[(long long)(m0 + (t >> 3) + 64 * i) * lda + kk],
              &As[slab * 16384 + (w * 8 + 64 * i) * 64]);
  };
  auto stB = [&](int slab, int tile) {
    const long long kk = kbase + (long long)tile * 64 + (((t & 7) ^ ((t >> 3) & 7)) * 8);
    #pragma unroll
    for (int i = 0; i < 2; ++i)
      gload16(&Bb[(long long)(n0 + (t >> 3) + 64 * i) * ldb + kk],
              &Bs[slab * 8192 + (w * 8 + 64 * i) * 64]);
  };

#define RDA(sl,fm,ks) \
  (*reinterpret_cast<const bf16x8*>(&As[(sl)*16384 + \
      (wr64 + (fm)*16 + l15)*64 + ((((ks)*4 + l4) ^ l7) * 8)]))
#define RDB(sl,fn,ks) \
  (*reinterpret_cast<const bf16x8*>(&Bs[(sl)*8192 + \
      (wc64 + (fn)*16 + l15)*64 + ((((ks)*4 + l4) ^ l7) * 8)]))

  f32x4 acc[4][4] = {};
  bf16x8 a_[4][2];
  bf16x8 b_[4][2];

#define BAR asm volatile("s_barrier" ::: "memory")
#define WAIT6 asm volatile("s_waitcnt vmcnt(6)" ::: "memory")
#define WAIT0 asm volatile("s_waitcnt vmcnt(0)" ::: "memory")

  stA(0, 0); stB(0, 0);
  stA(1, 1); stB(1, 1);
  WAIT6;
  BAR;

  const int nt = Ksub >> 6;
  int s0 = 0, s1 = 1, s2 = 2;
  for (int tt = 0; tt < nt; ++tt) {
    #pragma unroll
    for (int f = 0; f < 4; ++f) {
      a_[f][0] = RDA(s0, f, 0); a_[f][1] = RDA(s0, f, 1);
      b_[f][0] = RDB(s0, f, 0); b_[f][1] = RDB(s0, f, 1);
    }

    if (tt < nt - 2) { stA(s2, tt + 2); stB(s2, tt + 2); }

    __builtin_amdgcn_s_setprio(1);
    #pragma unroll
    for (int fm = 0; fm < 4; ++fm)
      #pragma unroll
      for (int fn = 0; fn < 4; ++fn) {
        acc[fm][fn] = __builtin_amdgcn_mfma_f32_16x16x32_bf16(
            a_[fm][0], b_[fn][0], acc[fm][fn], 0, 0, 0);
        acc[fm][fn] = __builtin_amdgcn_mfma_f32_16x16x32_bf16(
            a_[fm][1], b_[fn][1], acc[fm][fn], 0, 0, 0);
      }
    __builtin_amdgcn_s_setprio(0);

    if (tt < nt - 2)       { WAIT6; }
    else if (tt == nt - 2) { WAIT0; }
    BAR;

    const int tmp = s0; s0 = s1; s1 = s2; s2 = tmp;
  }
#undef RDA
#undef RDB
#undef BAR
#undef WAIT6
#undef WAIT0

  #pragma unroll
  for (int fm = 0; fm < 4; ++fm)
    #pragma unroll
    for (int r = 0; r < 4; ++r) {
      const long long row = m0 + wr64 + fm * 16 + l4 * 4 + r;
      #pragma unroll
      for (int fn = 0; fn < 4; ++fn) {
        const int lc = wc64 + fn * 16 + l15;
        Cp[row * (long long)ldc + n0 + lc] = acc[fm][fn][r];
      }
    }
}

// ---------------------------------------------------------------------------
// 2-phase bf16 MFMA GEMM (bf16 B via global_load_lds only).
// ---------------------------------------------------------------------------
constexpr int E_BIAS = 1, E_RES = 2, E_RELU = 4, E_WF32 = 8, E_WB16 = 16;

template<int BM, int BN, int WM, int WN, int EPI>
__global__ __launch_bounds__(256)
void gemm_bf16(const u16* __restrict__ A, const u16* __restrict__ Bw,
               const float* __restrict__ bias, const float* __restrict__ res,
               float* __restrict__ C, u16* __restrict__ Cb,
               int K, int lda, int ldb, int ldc, int nbz2,
               long long sA1, long long sA2, long long sB1, long long sB2,
               long long sC1, long long sC2, float alpha)
{
  constexpr int SM = BM / WM, SN = BN / WN;
  constexpr int FM = SM / 16, FN = SN / 16;
  constexpr int PA = BM / 64, PB = BN / 64;
  __shared__ __align__(16) u16 As[2][BM * 32];
  __shared__ __align__(16) u16 Bs[2][BN * 32];

  const int gx = gridDim.x, gy = gridDim.y;
  const int nwg = gx * gy * gridDim.z;
  const int flat = (blockIdx.z * gy + blockIdx.y) * gx + blockIdx.x;
  const int qq = nwg >> 3, rr = nwg & 7;
  const int xcd = flat & 7, lid = flat >> 3;
  const int wg = (xcd < rr ? xcd * (qq + 1) : rr * (qq + 1) + (xcd - rr) * qq) + lid;
  const int bx = wg % gx;
  const int tmp1 = wg / gx;
  const int by = tmp1 % gy, bz = tmp1 / gy;

  const int t = threadIdx.x;
  const int w = t >> 6, l = t & 63;
  const int wr = w / WN, wc = w % WN;
  const int m0 = by * BM, n0 = bx * BN;
  const long long offA = (long long)(bz / nbz2) * sA1 + (long long)(bz % nbz2) * sA2;
  const long long offB = (long long)(bz / nbz2) * sB1 + (long long)(bz % nbz2) * sB2;
  const long long offC = (long long)(bz / nbz2) * sC1 + (long long)(bz % nbz2) * sC2;
  const u16* Ab = A + offA;
  const u16* Bb = Bw + offB;

  const int srow = t >> 2;
  const int sk   = (t & 3) * 8;

  auto stageA = [&](int buf, int k0) {
    #pragma unroll
    for (int p = 0; p < PA; ++p)
      gload16(&Ab[(long long)(m0 + p * 64 + srow) * lda + k0 + sk],
              &As[buf][p * 2048 + w * 512]);
  };
  auto stageB = [&](int buf, int k0) {
    #pragma unroll
    for (int p = 0; p < PB; ++p)
      gload16(&Bb[(long long)(n0 + p * 64 + srow) * ldb + k0 + sk],
              &Bs[buf][p * 2048 + w * 512]);
  };

  f32x4 acc[FM][FN] = {};

  stageA(0, 0);
  stageB(0, 0);

  int cur = 0;
  for (int k0 = 0; k0 < K; k0 += 32) {
    __syncthreads();
    const bool pf = (k0 + 32 < K);
    if (pf) {
      stageA(cur ^ 1, k0 + 32);
      stageB(cur ^ 1, k0 + 32);
    }

    bf16x8 af[FM], bfr[FN];
    #pragma unroll
    for (int i = 0; i < FM; ++i)
      af[i] = *reinterpret_cast<const bf16x8*>(
          &As[cur][(wr * SM + i * 16 + (l & 15)) * 32 + (l >> 4) * 8]);
    #pragma unroll
    for (int j = 0; j < FN; ++j)
      bfr[j] = *reinterpret_cast<const bf16x8*>(
          &Bs[cur][(wc * SN + j * 16 + (l & 15)) * 32 + (l >> 4) * 8]);
    #pragma unroll
    for (int i = 0; i < FM; ++i)
      #pragma unroll
      for (int j = 0; j < FN; ++j)
        acc[i][j] = __builtin_amdgcn_mfma_f32_16x16x32_bf16(af[i], bfr[j], acc[i][j], 0, 0, 0);
    cur ^= 1;
  }

  const int c_l = l & 15, r_l4 = (l >> 4) * 4;
  #pragma unroll
  for (int i = 0; i < FM; ++i) {
    #pragma unroll
    for (int r = 0; r < 4; ++r) {
      const long long row = m0 + wr * SM + i * 16 + r_l4 + r;
      #pragma unroll
      for (int j = 0; j < FN; ++j) {
        const int col = n0 + wc * SN + j * 16 + c_l;
        float v = acc[i][j][r] * alpha;
        if (EPI & E_BIAS) v += bias[col];
        if (EPI & E_RES)  v += res[row * (long long)ldc + col];
        if (EPI & E_RELU) v = fmaxf(v, 0.f);
        const long long co = offC + row * (long long)ldc + col;
        if (EPI & E_WF32) C[co] = v;
        if (EPI & E_WB16) Cb[co] = f2b(v);
      }
    }
  }
}

// ---------------------------------------------------------------------------
__global__ __launch_bounds__(256)
void vox_prep(const float* __restrict__ in, u16* __restrict__ vb,
              u16* __restrict__ vt)
{
  __shared__ u16 tile[64][68];
  const int b = blockIdx.z;
  const int n0 = blockIdx.y * 64;
  const int d0 = blockIdx.x * 64;
  const int t = threadIdx.x;
  const int tr = t >> 4;
  const int tc = (t & 15) * 4;
  const float* ib = in + (long long)b * NV * D;
  u16* vbb = vb + (long long)b * NV * D;
  u16* vtb = vt + (long long)b * NV * D;
  #pragma unroll
  for (int p = 0; p < 4; ++p) {
    int r = tr + p * 16;
    float4 x = *reinterpret_cast<const float4*>(&ib[(long long)(n0 + r) * D + d0 + tc]);
    u16x4 o = {f2b(x.x), f2b(x.y), f2b(x.z), f2b(x.w)};
    *reinterpret_cast<u16x4*>(&vbb[(long long)(n0 + r) * D + d0 + tc]) = o;
    *reinterpret_cast<u16x4*>(&tile[r][tc]) = o;
  }
  __syncthreads();
  #pragma unroll
  for (int p = 0; p < 4; ++p) {
    int c = tr + p * 16;
    u16x4 o = {tile[tc + 0][c], tile[tc + 1][c], tile[tc + 2][c], tile[tc + 3][c]};
    *reinterpret_cast<u16x4*>(&vtb[(long long)(d0 + c) * NV + n0 + tc]) = o;
  }
}

// ---------------------------------------------------------------------------
struct Cvt8 { const float* s[8]; const float* s2[8]; u16* d[8]; int cum[9]; };

__global__ __launch_bounds__(256)
void cvt_multi(Cvt8 a)
{
  const int bidx = blockIdx.x;
  int seg = 0;
  #pragma unroll
  for (int k = 1; k < 8; ++k) if (bidx >= a.cum[k]) seg = k;
  const long long off = ((long long)(bidx - a.cum[seg]) * 256 + threadIdx.x) * 4;
  float4 x = *reinterpret_cast<const float4*>(a.s[seg] + off);
  if (a.s2[seg]) {
    float4 y = *reinterpret_cast<const float4*>(a.s2[seg] + off);
    x.x += y.x; x.y += y.y; x.z += y.z; x.w += y.w;
  }
  u16x4 o = {f2b(x.x), f2b(x.y), f2b(x.z), f2b(x.w)};
  *reinterpret_cast<u16x4*>(a.d[seg] + off) = o;
}

// ---------------------------------------------------------------------------
__global__ __launch_bounds__(256)
void ln_kernel(const float* __restrict__ x, const float* __restrict__ g,
               const float* __restrict__ bia, float* __restrict__ y,
               u16* __restrict__ yb, float scale)
{
  __shared__ float tmp[256];
  const int t = threadIdx.x;
  const long long off = (long long)blockIdx.x * D;
  float4 x4 = *reinterpret_cast<const float4*>(&x[off + t * 4]);
  tmp[t] = x4.x + x4.y + x4.z + x4.w;
  __syncthreads();
  for (int o = 128; o > 0; o >>= 1) { if (t < o) tmp[t] += tmp[t + o]; __syncthreads(); }
  const float mean = tmp[0] * (1.f / D);
  __syncthreads();
  float d0 = x4.x - mean, d1 = x4.y - mean, d2 = x4.z - mean, d3 = x4.w - mean;
  tmp[t] = d0 * d0 + d1 * d1 + d2 * d2 + d3 * d3;
  __syncthreads();
  for (int o = 128; o > 0; o >>= 1) { if (t < o) tmp[t] += tmp[t + o]; __syncthreads(); }
  const float rs = rsqrtf(tmp[0] * (1.f / D) + 1e-5f);
  float4 g4 = *reinterpret_cast<const float4*>(&g[t * 4]);
  float4 b4 = *reinterpret_cast<const float4*>(&bia[t * 4]);
  float o0 = (d0 * rs * g4.x + b4.x) * scale;
  float o1 = (d1 * rs * g4.y + b4.y) * scale;
  float o2 = (d2 * rs * g4.z + b4.z) * scale;
  float o3 = (d3 * rs * g4.w + b4.w) * scale;
  if (y) {
    float4 o4 = {o0, o1, o2, o3};
    *reinterpret_cast<float4*>(&y[off + t * 4]) = o4;
  }
  if (yb) {
    u16x4 ob = {f2b(o0), f2b(o1), f2b(o2), f2b(o3)};
    *reinterpret_cast<u16x4*>(&yb[off + t * 4]) = ob;
  }
}

// ---------------------------------------------------------------------------
__global__ __launch_bounds__(256)
void vox_softmax(float* __restrict__ s, const int* __restrict__ mask,
                 u16* __restrict__ wb)
{
  __shared__ float tmp[256];
  const int t = threadIdx.x;
  const int row = blockIdx.x, b = row / NQ;
  float* sr = s + (long long)row * NV;
  u16* wr = wb + (long long)row * NV;
  const int* mr = mask + b * NV;
  float vals[16];
  float lm = -INFINITY;
  #pragma unroll
  for (int j = 0; j < 16; ++j) {
    int n = t + j * 256;
    float x = mr[n] ? -INFINITY : sr[n];
    vals[j] = x;
    lm = fmaxf(lm, x);
  }
  tmp[t] = lm;
  __syncthreads();
  for (int o = 128; o > 0; o >>= 1) { if (t < o) tmp[t] = fmaxf(tmp[t], tmp[t + o]); __syncthreads(); }
  const float mx = tmp[0];
  __syncthreads();
  float ls = 0.f;
  #pragma unroll
  for (int j = 0; j < 16; ++j) { vals[j] = __expf(vals[j] - mx); ls += vals[j]; }
  tmp[t] = ls;
  __syncthreads();
  for (int o = 128; o > 0; o >>= 1) { if (t < o) tmp[t] += tmp[t + o]; __syncthreads(); }
  const float inv = 1.f / tmp[0];
  #pragma unroll
  for (int j = 0; j < 16; ++j) {
    float v = vals[j] * inv;
    sr[t + j * 256] = v;
    wr[t + j * 256] = f2b(v);
  }
}

__global__ __launch_bounds__(256)
void splitk_reduce(const float* __restrict__ part, float* __restrict__ out)
{
  const long long i = ((long long)blockIdx.x * 256 + threadIdx.x) * 4;
  const long long nd = (long long)NQ * D;
  const long long b = i / nd;
  const long long o = i - b * nd;
  const float* p = part + b * 4 * nd + o;
  float4 s0 = *reinterpret_cast<const float4*>(&p[0]);
  float4 s1 = *reinterpret_cast<const float4*>(&p[nd]);
  float4 s2 = *reinterpret_cast<const float4*>(&p[2 * nd]);
  float4 s3 = *reinterpret_cast<const float4*>(&p[3 * nd]);
  float4 r = {s0.x + s1.x + s2.x + s3.x, s0.y + s1.y + s2.y + s3.y,
              s0.z + s1.z + s2.z + s3.z, s0.w + s1.w + s2.w + s3.w};
  *reinterpret_cast<float4*>(&out[i]) = r;
}

// ---------------------------------------------------------------------------
extern "C" void kernel_launch(void* const* d_in, const int* in_sizes, int n_in,
                              void* d_out, int out_size, void* d_ws, size_t ws_size,
                              hipStream_t stream)
{
  const float* tgt   = (const float*)d_in[0];
  const float* mtxt  = (const float*)d_in[1];
  const float* vox   = (const float*)d_in[2];
  const float* qpos  = (const float*)d_in[3];
  const int*   mtx_m = (const int*)d_in[4];
  const int*   vox_m = (const int*)d_in[5];
  const float* Wq = (const float*)d_in[6];  const float* bq = (const float*)d_in[7];
  const float* Wk = (const float*)d_in[8];  const float* bk = (const float*)d_in[9];
  const float* Wv = (const float*)d_in[10]; const float* bv = (const float*)d_in[11];
  const float* Wo = (const float*)d_in[12]; const float* bo = (const float*)d_in[13];
  const float* W1 = (const float*)d_in[14]; const float* b1 = (const float*)d_in[15];
  const float* W2 = (const float*)d_in[16]; const float* b2 = (const float*)d_in[17];
  const float* ln1g = (const float*)d_in[18]; const float* ln1b = (const float*)d_in[19];
  const float* ln2g = (const float*)d_in[20]; const float* ln2b = (const float*)d_in[21];

  float* out0 = (float*)d_out;                       // attn_output  [B,NQ,D]
  float* out1 = out0 + (long long)B * NQ * D;        // txt_cross    [B,NQ,LT]
  float* out2 = out1 + (long long)B * NQ * LT;       // attn_weights [B,NQ,NV]

  char* base = (char*)d_ws;
  constexpr size_t MB = 1ull << 20;
  u16*   kvW   = (u16*)(base + 0 * MB);     // 16  [Wk;Wv] stacked
  u16*   Wq_b  = (u16*)(base + 16 * MB);    // 2
  u16*   Wo_b  = (u16*)(base + 18 * MB);    // 2
  u16*   W1_b  = (u16*)(base + 20 * MB);    // 4
  u16*   W2_b  = (u16*)(base + 24 * MB);    // 4
  u16*   tq_b  = (u16*)(base + 28 * MB);    // 4
  u16*   q_b   = (u16*)(base + 32 * MB);    // 4
  u16*   kv_b  = (u16*)(base + 36 * MB);    // 16  [B*LT][2048] (K half used)
  u16*   vT_b  = (u16*)(base + 52 * MB);    // 8   [B][D][LT]
  u16*   ctx_b = (u16*)(base + 60 * MB);    // 4
  float* x1p   = (float*)(base + 64 * MB);  // 8
  float* x1f   = (float*)(base + 72 * MB);  // 8
  u16*   x1_b  = (u16*)(base + 80 * MB);    // 4
  u16*   ff1_b = (u16*)(base + 84 * MB);    // 8
  float* x2p   = (float*)(base + 92 * MB);  // 8
  u16*   x2s_b = (u16*)(base + 100 * MB);   // 4
  u16*   mtxt_b = (u16*)(base + 104 * MB);  // 32  dead after kv256b
  u16*   vox_b  = (u16*)(base + 104 * MB);  // 64  overlays mtxt_b (dead)
  u16*   voxT_b = (u16*)(base + 168 * MB);  // 64
  u16*   wvox_b = (u16*)(base + 0 * MB);    // 16  overlays kvW (dead)
  float* part   = (float*)(base + 16 * MB); // 32  overlays Wq..q_b (dead)

  const dim3 blk(256);
  const long long nd = (long long)NQ * D;

  // 1) conversions: fused weights + memory_txt + (tgt+qpos)
  Cvt8 ca;
  for (int i = 0; i < 8; ++i) ca.s2[i] = nullptr;
  ca.s[0] = Wq;   ca.d[0] = Wq_b;
  ca.s[1] = Wk;   ca.d[1] = kvW;
  ca.s[2] = Wv;   ca.d[2] = kvW + (long long)D * FTXT;
  ca.s[3] = Wo;   ca.d[3] = Wo_b;
  ca.s[4] = W1;   ca.d[4] = W1_b;
  ca.s[5] = W2;   ca.d[5] = W2_b;
  ca.s[6] = mtxt; ca.d[6] = mtxt_b;
  ca.s[7] = tgt;  ca.s2[7] = qpos; ca.d[7] = tq_b;
  ca.cum[0] = 0;     ca.cum[1] = 1024;  ca.cum[2] = 5120;  ca.cum[3] = 9216;
  ca.cum[4] = 10240; ca.cum[5] = 12288; ca.cum[6] = 14336; ca.cum[7] = 30720;
  ca.cum[8] = 32768;
  cvt_multi<<<dim3(32768), blk, 0, stream>>>(ca);

  // 2) q projection (2-phase) + kv projection (merged-phase; V -> vT fused)
  gemm_bf16<64,64,2,2, E_BIAS|E_WB16><<<dim3(D/64, (B*NQ)/64, 1), blk, 0, stream>>>(
      tq_b, Wq_b, bq, nullptr, nullptr, q_b, D, D, D, D, 1, 0,0,0,0,0,0, 1.f);
  gemm_kv256b<<<dim3(16, 16), dim3(512), 0, stream>>>(mtxt_b, kvW, bk, bv, kv_b, vT_b);

  // 3) fused text attention (scores + softmax + head-mean + P@V)
  zero_out1<<<dim3((B * NQ * LT) / 1024), blk, 0, stream>>>(out1);
  fused_txt_attn<<<dim3(2, H, B), dim3(512), 0, stream>>>(
      q_b, kv_b, vT_b, mtx_m, ctx_b, out1);

  // 4) vox -> vox_b + voxT_b (one f32 read)
  vox_prep<<<dim3(D/64, NV/64, B), blk, 0, stream>>>(vox, vox_b, voxT_b);

  // 5) x1p = tgt + ctx @ Wo^T + bo
  gemm_bf16<64,64,2,2, E_BIAS|E_RES|E_WF32><<<dim3(D/64, (B*NQ)/64, 1), blk, 0, stream>>>(
      ctx_b, Wo_b, bo, tgt, x1p, nullptr, D, D, D, D, 1, 0,0,0,0,0,0, 1.f);

  // 6) LN1
  ln_kernel<<<dim3(B*NQ), blk, 0, stream>>>(x1p, ln1g, ln1b, x1f, x1_b, 1.f);

  // 7) ff1 = relu(x1 @ W1^T + b1)
  gemm_bf16<128,64,2,2, E_BIAS|E_RELU|E_WB16><<<dim3(DFF/64, (B*NQ)/128, 1), blk, 0, stream>>>(
      x1_b, W1_b, b1, nullptr, nullptr, ff1_b, D, D, D, DFF, 1, 0,0,0,0,0,0, 1.f);

  // 8) x2p = x1 + ff1 @ W2^T + b2
  gemm_bf16<64,64,2,2, E_BIAS|E_RES|E_WF32><<<dim3(D/64, (B*NQ)/64, 1), blk, 0, stream>>>(
      ff1_b, W2_b, b2, x1f, x2p, nullptr, DFF, DFF, DFF, D, 1, 0,0,0,0,0,0, 1.f);

  // 9) LN2 -> x2s (bf16, /sqrt(D))
  ln_kernel<<<dim3(B*NQ), blk, 0, stream>>>(x2p, ln2g, ln2b, nullptr, x2s_b, 0.03125f);

  // 10) out2 = x2s @ vox_b^T  (merged-phase)
  gemm8<1><<<dim3(NV/128, 1, B), dim3(512), 0, stream>>>(
      x2s_b, vox_b, out2, D, D, D, NV, 0,
      nd, (long long)NV * D, (long long)NQ * NV, 0);

  // 11) masked softmax in place; bf16 weights
  vox_softmax<<<dim3(B*NQ), blk, 0, stream>>>(out2, vox_m, wvox_b);

  // 12) out0 partials: merged-phase split-K=4 + reduce
  gemm8<4><<<dim3(D/128, 1, B*4), dim3(512), 0, stream>>>(
      wvox_b, voxT_b, part, NV/4, NV, NV, D, NV/4,
      (long long)NQ * NV, (long long)D * NV, 4 * nd, nd);
  splitk_reduce<<<dim3((B * NQ * D) / 1024), blk, 0, stream>>>(part, out0);
}

// Round 18
// 370.107 us; speedup vs baseline: 1.1097x; 1.1088x over previous
//
#include <hip/hip_runtime.h>
#include <math.h>

typedef unsigned short u16;
typedef unsigned int u32;
typedef __bf16 bf16x8 __attribute__((ext_vector_type(8)));
typedef float f32x4 __attribute__((ext_vector_type(4)));
typedef u16 u16x4 __attribute__((ext_vector_type(4)));
typedef u16 u16x2 __attribute__((ext_vector_type(2)));

constexpr int B = 8, NQ = 256, LT = 512, NV = 4096;
constexpr int D = 1024, H = 16, DFF = 2048, FTXT = 4096, HD = 64;

__device__ __forceinline__ u16 f2b(float f) {
  u32 u = __builtin_bit_cast(u32, f);
  return (u16)((u + 0x7fffu + ((u >> 16) & 1u)) >> 16);   // RNE
}
__device__ __forceinline__ float b2f(u16 b) {
  u32 u = ((u32)b) << 16;
  return __builtin_bit_cast(float, u);
}
__device__ __forceinline__ void gload16(const void* g, void* l) {
  __builtin_amdgcn_global_load_lds(
      (const __attribute__((address_space(1))) u32*)g,
      (__attribute__((address_space(3))) u32*)l, 16, 0, 0);
}

// ===========================================================================
// Fused text attention: one block per (qhalf, h, b). 512 thr = 8 waves.
// R18: out1 atomics removed -> P copied coalesced to w_b (bf16);
// head-mean done by separate head_mean kernel (R15-proven numerics).
// ===========================================================================
__global__ __launch_bounds__(512, 1)
void fused_txt_attn(const u16* __restrict__ qb, const u16* __restrict__ kvb,
                    const u16* __restrict__ vT, const int* __restrict__ mask,
                    u16* __restrict__ ctx, u16* __restrict__ wout)
{
  __shared__ __align__(16) u16 lds[78848];   // 154 KB
  u16* Qs = lds;                 // [128][64] bf16 @ 0      (16 KB)
  u16* Ks = lds + 8192;          // [512][64] bf16 @ 16 KB  (64 KB)
  u16* Ps = lds;                 // 8 x [128][64] bf16 @ 0  (128 KB, after barrier)
  u16* Vs = lds + 65536;         // 3 x [64][64] bf16       (24 KB)
  float* red = (float*)(lds + 77824);  // [128][4] f32 (2 KB)

  const int qhalf = blockIdx.x, h = blockIdx.y, b = blockIdx.z;
  const int t = threadIdx.x;
  const int w = t >> 6, l = t & 63;
  const int l15 = l & 15, l4 = l >> 4;
  const int wr64 = (w >> 2) * 64;        // 2 row-waves (q)
  const int wc128 = (w & 3) * 128;       // 4 col-waves (kv)
  const int q0 = b * NQ + qhalf * 128;   // global q row base

  // ---- stage Q (2 gloads) + K (8 gloads), swizzled ----
  {
    const int srow = t >> 3;
    const int sch = (t & 7) ^ (srow & 7);
    #pragma unroll
    for (int i = 0; i < 2; ++i)
      gload16(&qb[(long long)(q0 + srow + 64 * i) * D + h * HD + sch * 8],
              &Qs[(srow + 64 * i) * 64]);
    #pragma unroll
    for (int i = 0; i < 8; ++i)
      gload16(&kvb[(long long)(b * LT + srow + 64 * i) * 2048 + h * HD + sch * 8],
              &Ks[(srow + 64 * i) * 64]);
  }
  asm volatile("s_waitcnt vmcnt(0)" ::: "memory");
  __syncthreads();

  // ---- S = Q @ K^T ----
  f32x4 acc[4][8];
  {
    bf16x8 a_[4][2], b_[8][2];
    #pragma unroll
    for (int fm = 0; fm < 4; ++fm) {
      const int r = wr64 + fm * 16 + l15;
      a_[fm][0] = *reinterpret_cast<const bf16x8*>(&Qs[r * 64 + (((0 * 4 + l4) ^ (r & 7)) * 8)]);
      a_[fm][1] = *reinterpret_cast<const bf16x8*>(&Qs[r * 64 + (((1 * 4 + l4) ^ (r & 7)) * 8)]);
    }
    #pragma unroll
    for (int fn = 0; fn < 8; ++fn) {
      const int r = wc128 + fn * 16 + l15;
      b_[fn][0] = *reinterpret_cast<const bf16x8*>(&Ks[r * 64 + (((0 * 4 + l4) ^ (r & 7)) * 8)]);
      b_[fn][1] = *reinterpret_cast<const bf16x8*>(&Ks[r * 64 + (((1 * 4 + l4) ^ (r & 7)) * 8)]);
    }
    #pragma unroll
    for (int fm = 0; fm < 4; ++fm)
      #pragma unroll
      for (int fn = 0; fn < 8; ++fn) {
        f32x4 c = {0.f, 0.f, 0.f, 0.f};
        c = __builtin_amdgcn_mfma_f32_16x16x32_bf16(a_[fm][0], b_[fn][0], c, 0, 0, 0);
        c = __builtin_amdgcn_mfma_f32_16x16x32_bf16(a_[fm][1], b_[fn][1], c, 0, 0, 0);
        acc[fm][fn] = c;
      }
  }

  // ---- mask + scale ----
  int mk[8];
  #pragma unroll
  for (int fn = 0; fn < 8; ++fn) mk[fn] = mask[b * LT + wc128 + fn * 16 + l15];
  #pragma unroll
  for (int fm = 0; fm < 4; ++fm)
    #pragma unroll
    for (int fn = 0; fn < 8; ++fn)
      #pragma unroll
      for (int r = 0; r < 4; ++r)
        acc[fm][fn][r] = mk[fn] ? -INFINITY : acc[fm][fn][r] * 0.125f;

  // ---- row max ----
  float mx[4][4];
  #pragma unroll
  for (int fm = 0; fm < 4; ++fm)
    #pragma unroll
    for (int r = 0; r < 4; ++r) {
      float m = acc[fm][0][r];
      #pragma unroll
      for (int fn = 1; fn < 8; ++fn) m = fmaxf(m, acc[fm][fn][r]);
      #pragma unroll
      for (int o = 1; o < 16; o <<= 1) m = fmaxf(m, __shfl_xor(m, o, 64));
      mx[fm][r] = m;
    }
  if (l15 == 0) {
    #pragma unroll
    for (int fm = 0; fm < 4; ++fm)
      #pragma unroll
      for (int r = 0; r < 4; ++r)
        red[(wr64 + fm * 16 + l4 * 4 + r) * 4 + (w & 3)] = mx[fm][r];
  }
  __syncthreads();
  #pragma unroll
  for (int fm = 0; fm < 4; ++fm)
    #pragma unroll
    for (int r = 0; r < 4; ++r) {
      const int row = wr64 + fm * 16 + l4 * 4 + r;
      mx[fm][r] = fmaxf(fmaxf(red[row * 4 + 0], red[row * 4 + 1]),
                        fmaxf(red[row * 4 + 2], red[row * 4 + 3]));
    }
  __syncthreads();

  // ---- exp + row sum ----
  float sm[4][4];
  #pragma unroll
  for (int fm = 0; fm < 4; ++fm)
    #pragma unroll
    for (int r = 0; r < 4; ++r) {
      float s = 0.f;
      #pragma unroll
      for (int fn = 0; fn < 8; ++fn) {
        float e = __expf(acc[fm][fn][r] - mx[fm][r]);
        acc[fm][fn][r] = e;
        s += e;
      }
      #pragma unroll
      for (int o = 1; o < 16; o <<= 1) s += __shfl_xor(s, o, 64);
      sm[fm][r] = s;
    }
  if (l15 == 0) {
    #pragma unroll
    for (int fm = 0; fm < 4; ++fm)
      #pragma unroll
      for (int r = 0; r < 4; ++r)
        red[(wr64 + fm * 16 + l4 * 4 + r) * 4 + (w & 3)] = sm[fm][r];
  }
  __syncthreads();
  #pragma unroll
  for (int fm = 0; fm < 4; ++fm)
    #pragma unroll
    for (int r = 0; r < 4; ++r) {
      const int row = wr64 + fm * 16 + l4 * 4 + r;
      sm[fm][r] = 1.f / (red[row * 4 + 0] + red[row * 4 + 1] +
                         red[row * 4 + 2] + red[row * 4 + 3]);
    }
  __syncthreads();

  // ---- p = e*inv ; P -> LDS bf16 (swizzled) ----
  #pragma unroll
  for (int fm = 0; fm < 4; ++fm)
    #pragma unroll
    for (int r = 0; r < 4; ++r) {
      const int row = wr64 + fm * 16 + l4 * 4 + r;
      #pragma unroll
      for (int fn = 0; fn < 8; ++fn) {
        const int col = wc128 + fn * 16 + l15;
        const float p = acc[fm][fn][r] * sm[fm][r];
        const int kt = col >> 6, c6 = col & 63;
        Ps[kt * 8192 + row * 64 + (((c6 >> 3) ^ (row & 7)) * 8) + (c6 & 7)] = f2b(p);
      }
    }
  __syncthreads();

  // ---- issue first V loads, then coalesced w store from Ps ----
  auto stV = [&](int slab, int kt) {
    const int srow = t >> 3;
    const int sch = (t & 7) ^ (srow & 7);
    gload16(&vT[((long long)b * D + h * HD + srow) * LT + kt * 64 + sch * 8],
            &Vs[slab * 4096 + srow * 64]);
  };
  stV(0, 0); stV(1, 1);

  {
    const long long wbase = (((long long)(b * H + h)) * NQ + qhalf * 128) * LT;
    #pragma unroll
    for (int j = 0; j < 16; ++j) {
      const int chunk = t + j * 512;        // 8192 chunks of 8 elems
      const int kt = chunk >> 10;
      const int c = chunk & 1023;
      const int row = c >> 3;
      const int s = c & 7;
      bf16x8 v = *reinterpret_cast<const bf16x8*>(&Ps[kt * 8192 + row * 64 + s * 8]);
      const int g = s ^ (row & 7);
      *reinterpret_cast<bf16x8*>(&wout[wbase + (long long)row * LT + kt * 64 + g * 8]) = v;
    }
  }

  asm volatile("s_waitcnt vmcnt(1)" ::: "memory");
  __syncthreads();

  // ---- PV: ctx = P @ vT^T, V streamed in 8 tiles (3-slab) ----
  f32x4 acc2[4] = {};
  const int pvr = w * 16;
  int s0 = 0, s1 = 1, s2 = 2;
  for (int kt = 0; kt < 8; ++kt) {
    bf16x8 pa[2], vb[4][2];
    {
      const int r = pvr + l15;
      pa[0] = *reinterpret_cast<const bf16x8*>(&Ps[kt * 8192 + r * 64 + (((0 * 4 + l4) ^ (r & 7)) * 8)]);
      pa[1] = *reinterpret_cast<const bf16x8*>(&Ps[kt * 8192 + r * 64 + (((1 * 4 + l4) ^ (r & 7)) * 8)]);
      #pragma unroll
      for (int fn = 0; fn < 4; ++fn) {
        const int vr = fn * 16 + l15;
        vb[fn][0] = *reinterpret_cast<const bf16x8*>(&Vs[s0 * 4096 + vr * 64 + (((0 * 4 + l4) ^ (vr & 7)) * 8)]);
        vb[fn][1] = *reinterpret_cast<const bf16x8*>(&Vs[s0 * 4096 + vr * 64 + (((1 * 4 + l4) ^ (vr & 7)) * 8)]);
      }
    }
    if (kt < 6) stV(s2, kt + 2);
    #pragma unroll
    for (int fn = 0; fn < 4; ++fn) {
      acc2[fn] = __builtin_amdgcn_mfma_f32_16x16x32_bf16(pa[0], vb[fn][0], acc2[fn], 0, 0, 0);
      acc2[fn] = __builtin_amdgcn_mfma_f32_16x16x32_bf16(pa[1], vb[fn][1], acc2[fn], 0, 0, 0);
    }
    if (kt < 6)       { asm volatile("s_waitcnt vmcnt(1)" ::: "memory"); }
    else if (kt == 6) { asm volatile("s_waitcnt vmcnt(0)" ::: "memory"); }
    __syncthreads();
    const int tmp = s0; s0 = s1; s1 = s2; s2 = tmp;
  }

  #pragma unroll
  for (int fn = 0; fn < 4; ++fn)
    #pragma unroll
    for (int r = 0; r < 4; ++r) {
      const int row = pvr + l4 * 4 + r;
      ctx[(long long)(q0 + row) * D + h * HD + fn * 16 + l15] = f2b(acc2[fn][r]);
    }
}

// out1[b,q,l] = mean over h of w_bf[b,h,q,l]  (R3-proven, vectorized x2)
__global__ __launch_bounds__(256)
void head_mean(const u16* __restrict__ w, float* __restrict__ out1)
{
  const long long idx = ((long long)blockIdx.x * 256 + threadIdx.x) * 2;  // B*NQ*LT
  const int b = (int)(idx >> 17);               // NQ*LT = 131072
  const long long ql = idx & 131071;
  const u16* p = w + ((long long)b * H) * 131072 + ql;
  float s0 = 0.f, s1 = 0.f;
  #pragma unroll
  for (int h = 0; h < H; ++h) {
    const u16x2 v = *reinterpret_cast<const u16x2*>(&p[(long long)h * 131072]);
    s0 += b2f(v[0]); s1 += b2f(v[1]);
  }
  float2 o = {s0 * (1.f / H), s1 * (1.f / H)};
  *reinterpret_cast<float2*>(&out1[idx]) = o;
}

// ===========================================================================
// Merged-phase 256x128 schedule (R13/R15-verified).
// ===========================================================================
__global__ __launch_bounds__(512, 2)
void gemm_kv256b(const u16* __restrict__ A, const u16* __restrict__ Bw,
                 const float* __restrict__ bk_, const float* __restrict__ bv_,
                 u16* __restrict__ Cb, u16* __restrict__ vT)
{
  __shared__ __align__(16) u16 As[3 * 16384];
  __shared__ __align__(16) u16 Bs[3 * 8192];

  const int gx = 16;
  const int flat = blockIdx.y * gx + blockIdx.x;
  const int qq = 256 >> 3;
  const int xcd = flat & 7, lid = flat >> 3;
  const int wg = xcd * qq + lid;
  const int bx = wg % gx;
  const int by = wg / gx;
  const int m0 = by * 256, n0 = bx * 128;
  const float* bias = (n0 < 1024) ? (bk_ + n0) : (bv_ + (n0 - 1024));

  const int t = threadIdx.x;
  const int w = t >> 6, l = t & 63;
  const int wr64 = (w >> 1) * 64;
  const int wc64 = (w & 1) * 64;
  const int l15 = l & 15, l4 = l >> 4, l7 = l & 7;

  auto stA = [&](int slab, int tile) {
    const long long kk = (long long)tile * 64 + (((t & 7) ^ ((t >> 3) & 7)) * 8);
    #pragma unroll
    for (int i = 0; i < 4; ++i)
      gload16(&A[(long long)(m0 + (t >> 3) + 64 * i) * 4096 + kk],
              &As[slab * 16384 + (w * 8 + 64 * i) * 64]);
  };
  auto stB = [&](int slab, int tile) {
    const long long kk = (long long)tile * 64 + (((t & 7) ^ ((t >> 3) & 7)) * 8);
    #pragma unroll
    for (int i = 0; i < 2; ++i)
      gload16(&Bw[(long long)(n0 + (t >> 3) + 64 * i) * 4096 + kk],
              &Bs[slab * 8192 + (w * 8 + 64 * i) * 64]);
  };

#define RDA(sl,fm,ks) \
  (*reinterpret_cast<const bf16x8*>(&As[(sl)*16384 + \
      (wr64 + (fm)*16 + l15)*64 + ((((ks)*4 + l4) ^ l7) * 8)]))
#define RDB(sl,fn,ks) \
  (*reinterpret_cast<const bf16x8*>(&Bs[(sl)*8192 + \
      (wc64 + (fn)*16 + l15)*64 + ((((ks)*4 + l4) ^ l7) * 8)]))

  f32x4 acc[4][4] = {};
  bf16x8 a_[4][2];
  bf16x8 b_[4][2];

#define BAR asm volatile("s_barrier" ::: "memory")
#define WAIT6 asm volatile("s_waitcnt vmcnt(6)" ::: "memory")
#define WAIT0 asm volatile("s_waitcnt vmcnt(0)" ::: "memory")

  stA(0, 0); stB(0, 0);
  stA(1, 1); stB(1, 1);
  WAIT6;
  BAR;

  int s0 = 0, s1 = 1, s2 = 2;
  for (int tt = 0; tt < 64; ++tt) {
    #pragma unroll
    for (int f = 0; f < 4; ++f) {
      a_[f][0] = RDA(s0, f, 0); a_[f][1] = RDA(s0, f, 1);
      b_[f][0] = RDB(s0, f, 0); b_[f][1] = RDB(s0, f, 1);
    }

    if (tt < 62) { stA(s2, tt + 2); stB(s2, tt + 2); }

    __builtin_amdgcn_s_setprio(1);
    #pragma unroll
    for (int fm = 0; fm < 4; ++fm)
      #pragma unroll
      for (int fn = 0; fn < 4; ++fn) {
        acc[fm][fn] = __builtin_amdgcn_mfma_f32_16x16x32_bf16(
            a_[fm][0], b_[fn][0], acc[fm][fn], 0, 0, 0);
        acc[fm][fn] = __builtin_amdgcn_mfma_f32_16x16x32_bf16(
            a_[fm][1], b_[fn][1], acc[fm][fn], 0, 0, 0);
      }
    __builtin_amdgcn_s_setprio(0);

    if (tt < 62)       { WAIT6; }
    else if (tt == 62) { WAIT0; }
    BAR;

    const int tmp = s0; s0 = s1; s1 = s2; s2 = tmp;
  }
#undef RDA
#undef RDB
#undef BAR
#undef WAIT6
#undef WAIT0

  if (n0 < 1024) {
    #pragma unroll
    for (int fm = 0; fm < 4; ++fm)
      #pragma unroll
      for (int r = 0; r < 4; ++r) {
        const long long row = m0 + wr64 + fm * 16 + l4 * 4 + r;
        #pragma unroll
        for (int fn = 0; fn < 4; ++fn) {
          const int lc = wc64 + fn * 16 + l15;
          Cb[row * 2048 + n0 + lc] = f2b(acc[fm][fn][r] + bias[lc]);
        }
      }
  } else {
    #pragma unroll
    for (int fm = 0; fm < 4; ++fm) {
      const int row0 = m0 + wr64 + fm * 16 + l4 * 4;
      const int bb = row0 >> 9;
      const int l0 = row0 & 511;
      #pragma unroll
      for (int fn = 0; fn < 4; ++fn) {
        const int lc = wc64 + fn * 16 + l15;
        const int d = n0 + lc - 1024;
        const float bi = bias[lc];
        u16x4 o = {f2b(acc[fm][fn][0] + bi), f2b(acc[fm][fn][1] + bi),
                   f2b(acc[fm][fn][2] + bi), f2b(acc[fm][fn][3] + bi)};
        *reinterpret_cast<u16x4*>(&vT[((long long)bb * D + d) * LT + l0]) = o;
      }
    }
  }
}

template<int NZ2>
__global__ __launch_bounds__(512, 2)
void gemm8(const u16* __restrict__ A, const u16* __restrict__ Bw,
           float* __restrict__ C,
           int Ksub, int lda, int ldb, int ldc, int kstep,
           long long sA1, long long sB1, long long sC1, long long sC2)
{
  __shared__ __align__(16) u16 As[3 * 16384];
  __shared__ __align__(16) u16 Bs[3 * 8192];

  const int gx = gridDim.x, gy = gridDim.y;
  const int nwg = gx * gy * gridDim.z;
  const int flat = (blockIdx.z * gy + blockIdx.y) * gx + blockIdx.x;
  const int qq = nwg >> 3, rr = nwg & 7;
  const int xcd = flat & 7, lid = flat >> 3;
  const int wg = (xcd < rr ? xcd * (qq + 1) : rr * (qq + 1) + (xcd - rr) * qq) + lid;
  const int bx = wg % gx;
  const int tmp1 = wg / gx;
  const int by = tmp1 % gy, bz = tmp1 / gy;
  const int z1 = bz / NZ2, z2 = bz % NZ2;
  const int m0 = by * 256, n0 = bx * 128;
  const long long kbase = (long long)z2 * kstep;
  const u16* Ab = A + (long long)z1 * sA1;
  const u16* Bb = Bw + (long long)z1 * sB1;
  float* Cp = C + (long long)z1 * sC1 + (long long)z2 * sC2;

  const int t = threadIdx.x;
  const int w = t >> 6, l = t & 63;
  const int wr64 = (w >> 1) * 64;
  const int wc64 = (w & 1) * 64;
  const int l15 = l & 15, l4 = l >> 4, l7 = l & 7;

  auto stA = [&](int slab, int tile) {
    const long long kk = kbase + (long long)tile * 64 + (((t & 7) ^ ((t >> 3) & 7)) * 8);
    #pragma unroll
    for (int i = 0; i < 4; ++i)
      gload16(&Ab[(long long)(m0 + (t >> 3) + 64 * i) * lda + kk],
              &As[slab * 16384 + (w * 8 + 64 * i) * 64]);
  };
  auto stB = [&](int slab, int tile) {
    const long long kk = kbase + (long long)tile * 64 + (((t & 7) ^ ((t >> 3) & 7)) * 8);
    #pragma unroll
    for (int i = 0; i < 2; ++i)
      gload16(&Bb[(long long)(n0 + (t >> 3) + 64 * i) * ldb + kk],
              &Bs[slab * 8192 + (w * 8 + 64 * i) * 64]);
  };

#define RDA(sl,fm,ks) \
  (*reinterpret_cast<const bf16x8*>(&As[(sl)*16384 + \
      (wr64 + (fm)*16 + l15)*64 + ((((ks)*4 + l4) ^ l7) * 8)]))
#define RDB(sl,fn,ks) \
  (*reinterpret_cast<const bf16x8*>(&Bs[(sl)*8192 + \
      (wc64 + (fn)*16 + l15)*64 + ((((ks)*4 + l4) ^ l7) * 8)]))

  f32x4 acc[4][4] = {};
  bf16x8 a_[4][2];
  bf16x8 b_[4][2];

#define BAR asm volatile("s_barrier" ::: "memory")
#define WAIT6 asm volatile("s_waitcnt vmcnt(6)" ::: "memory")
#define WAIT0 asm volatile("s_waitcnt vmcnt(0)" ::: "memory")

  stA(0, 0); stB(0, 0);
  stA(1, 1); stB(1, 1);
  WAIT6;
  BAR;

  const int nt = Ksub >> 6;
  int s0 = 0, s1 = 1, s2 = 2;
  for (int tt = 0; tt < nt; ++tt) {
    #pragma unroll
    for (int f = 0; f < 4; ++f) {
      a_[f][0] = RDA(s0, f, 0); a_[f][1] = RDA(s0, f, 1);
      b_[f][0] = RDB(s0, f, 0); b_[f][1] = RDB(s0, f, 1);
    }

    if (tt < nt - 2) { stA(s2, tt + 2); stB(s2, tt + 2); }

    __builtin_amdgcn_s_setprio(1);
    #pragma unroll
    for (int fm = 0; fm < 4; ++fm)
      #pragma unroll
      for (int fn = 0; fn < 4; ++fn) {
        acc[fm][fn] = __builtin_amdgcn_mfma_f32_16x16x32_bf16(
            a_[fm][0], b_[fn][0], acc[fm][fn], 0, 0, 0);
        acc[fm][fn] = __builtin_amdgcn_mfma_f32_16x16x32_bf16(
            a_[fm][1], b_[fn][1], acc[fm][fn], 0, 0, 0);
      }
    __builtin_amdgcn_s_setprio(0);

    if (tt < nt - 2)       { WAIT6; }
    else if (tt == nt - 2) { WAIT0; }
    BAR;

    const int tmp = s0; s0 = s1; s1 = s2; s2 = tmp;
  }
#undef RDA
#undef RDB
#undef BAR
#undef WAIT6
#undef WAIT0

  #pragma unroll
  for (int fm = 0; fm < 4; ++fm)
    #pragma unroll
    for (int r = 0; r < 4; ++r) {
      const long long row = m0 + wr64 + fm * 16 + l4 * 4 + r;
      #pragma unroll
      for (int fn = 0; fn < 4; ++fn) {
        const int lc = wc64 + fn * 16 + l15;
        Cp[row * (long long)ldc + n0 + lc] = acc[fm][fn][r];
      }
    }
}

// ---------------------------------------------------------------------------
// 2-phase bf16 MFMA GEMM (bf16 B via global_load_lds only).
// ---------------------------------------------------------------------------
constexpr int E_BIAS = 1, E_RES = 2, E_RELU = 4, E_WF32 = 8, E_WB16 = 16;

template<int BM, int BN, int WM, int WN, int EPI>
__global__ __launch_bounds__(256)
void gemm_bf16(const u16* __restrict__ A, const u16* __restrict__ Bw,
               const float* __restrict__ bias, const float* __restrict__ res,
               float* __restrict__ C, u16* __restrict__ Cb,
               int K, int lda, int ldb, int ldc, int nbz2,
               long long sA1, long long sA2, long long sB1, long long sB2,
               long long sC1, long long sC2, float alpha)
{
  constexpr int SM = BM / WM, SN = BN / WN;
  constexpr int FM = SM / 16, FN = SN / 16;
  constexpr int PA = BM / 64, PB = BN / 64;
  __shared__ __align__(16) u16 As[2][BM * 32];
  __shared__ __align__(16) u16 Bs[2][BN * 32];

  const int gx = gridDim.x, gy = gridDim.y;
  const int nwg = gx * gy * gridDim.z;
  const int flat = (blockIdx.z * gy + blockIdx.y) * gx + blockIdx.x;
  const int qq = nwg >> 3, rr = nwg & 7;
  const int xcd = flat & 7, lid = flat >> 3;
  const int wg = (xcd < rr ? xcd * (qq + 1) : rr * (qq + 1) + (xcd - rr) * qq) + lid;
  const int bx = wg % gx;
  const int tmp1 = wg / gx;
  const int by = tmp1 % gy, bz = tmp1 / gy;

  const int t = threadIdx.x;
  const int w = t >> 6, l = t & 63;
  const int wr = w / WN, wc = w % WN;
  const int m0 = by * BM, n0 = bx * BN;
  const long long offA = (long long)(bz / nbz2) * sA1 + (long long)(bz % nbz2) * sA2;
  const long long offB = (long long)(bz / nbz2) * sB1 + (long long)(bz % nbz2) * sB2;
  const long long offC = (long long)(bz / nbz2) * sC1 + (long long)(bz % nbz2) * sC2;
  const u16* Ab = A + offA;
  const u16* Bb = Bw + offB;

  const int srow = t >> 2;
  const int sk   = (t & 3) * 8;

  auto stageA = [&](int buf, int k0) {
    #pragma unroll
    for (int p = 0; p < PA; ++p)
      gload16(&Ab[(long long)(m0 + p * 64 + srow) * lda + k0 + sk],
              &As[buf][p * 2048 + w * 512]);
  };
  auto stageB = [&](int buf, int k0) {
    #pragma unroll
    for (int p = 0; p < PB; ++p)
      gload16(&Bb[(long long)(n0 + p * 64 + srow) * ldb + k0 + sk],
              &Bs[buf][p * 2048 + w * 512]);
  };

  f32x4 acc[FM][FN] = {};

  stageA(0, 0);
  stageB(0, 0);

  int cur = 0;
  for (int k0 = 0; k0 < K; k0 += 32) {
    __syncthreads();
    const bool pf = (k0 + 32 < K);
    if (pf) {
      stageA(cur ^ 1, k0 + 32);
      stageB(cur ^ 1, k0 + 32);
    }

    bf16x8 af[FM], bfr[FN];
    #pragma unroll
    for (int i = 0; i < FM; ++i)
      af[i] = *reinterpret_cast<const bf16x8*>(
          &As[cur][(wr * SM + i * 16 + (l & 15)) * 32 + (l >> 4) * 8]);
    #pragma unroll
    for (int j = 0; j < FN; ++j)
      bfr[j] = *reinterpret_cast<const bf16x8*>(
          &Bs[cur][(wc * SN + j * 16 + (l & 15)) * 32 + (l >> 4) * 8]);
    #pragma unroll
    for (int i = 0; i < FM; ++i)
      #pragma unroll
      for (int j = 0; j < FN; ++j)
        acc[i][j] = __builtin_amdgcn_mfma_f32_16x16x32_bf16(af[i], bfr[j], acc[i][j], 0, 0, 0);
    cur ^= 1;
  }

  const int c_l = l & 15, r_l4 = (l >> 4) * 4;
  #pragma unroll
  for (int i = 0; i < FM; ++i) {
    #pragma unroll
    for (int r = 0; r < 4; ++r) {
      const long long row = m0 + wr * SM + i * 16 + r_l4 + r;
      #pragma unroll
      for (int j = 0; j < FN; ++j) {
        const int col = n0 + wc * SN + j * 16 + c_l;
        float v = acc[i][j][r] * alpha;
        if (EPI & E_BIAS) v += bias[col];
        if (EPI & E_RES)  v += res[row * (long long)ldc + col];
        if (EPI & E_RELU) v = fmaxf(v, 0.f);
        const long long co = offC + row * (long long)ldc + col;
        if (EPI & E_WF32) C[co] = v;
        if (EPI & E_WB16) Cb[co] = f2b(v);
      }
    }
  }
}

// ---------------------------------------------------------------------------
__global__ __launch_bounds__(256)
void vox_prep(const float* __restrict__ in, u16* __restrict__ vb,
              u16* __restrict__ vt)
{
  __shared__ u16 tile[64][68];
  const int b = blockIdx.z;
  const int n0 = blockIdx.y * 64;
  const int d0 = blockIdx.x * 64;
  const int t = threadIdx.x;
  const int tr = t >> 4;
  const int tc = (t & 15) * 4;
  const float* ib = in + (long long)b * NV * D;
  u16* vbb = vb + (long long)b * NV * D;
  u16* vtb = vt + (long long)b * NV * D;
  #pragma unroll
  for (int p = 0; p < 4; ++p) {
    int r = tr + p * 16;
    float4 x = *reinterpret_cast<const float4*>(&ib[(long long)(n0 + r) * D + d0 + tc]);
    u16x4 o = {f2b(x.x), f2b(x.y), f2b(x.z), f2b(x.w)};
    *reinterpret_cast<u16x4*>(&vbb[(long long)(n0 + r) * D + d0 + tc]) = o;
    *reinterpret_cast<u16x4*>(&tile[r][tc]) = o;
  }
  __syncthreads();
  #pragma unroll
  for (int p = 0; p < 4; ++p) {
    int c = tr + p * 16;
    u16x4 o = {tile[tc + 0][c], tile[tc + 1][c], tile[tc + 2][c], tile[tc + 3][c]};
    *reinterpret_cast<u16x4*>(&vtb[(long long)(d0 + c) * NV + n0 + tc]) = o;
  }
}

// ---------------------------------------------------------------------------
struct Cvt8 { const float* s[8]; const float* s2[8]; u16* d[8]; int cum[9]; };

__global__ __launch_bounds__(256)
void cvt_multi(Cvt8 a)
{
  const int bidx = blockIdx.x;
  int seg = 0;
  #pragma unroll
  for (int k = 1; k < 8; ++k) if (bidx >= a.cum[k]) seg = k;
  const long long off = ((long long)(bidx - a.cum[seg]) * 256 + threadIdx.x) * 4;
  float4 x = *reinterpret_cast<const float4*>(a.s[seg] + off);
  if (a.s2[seg]) {
    float4 y = *reinterpret_cast<const float4*>(a.s2[seg] + off);
    x.x += y.x; x.y += y.y; x.z += y.z; x.w += y.w;
  }
  u16x4 o = {f2b(x.x), f2b(x.y), f2b(x.z), f2b(x.w)};
  *reinterpret_cast<u16x4*>(a.d[seg] + off) = o;
}

// ---------------------------------------------------------------------------
__global__ __launch_bounds__(256)
void ln_kernel(const float* __restrict__ x, const float* __restrict__ g,
               const float* __restrict__ bia, float* __restrict__ y,
               u16* __restrict__ yb, float scale)
{
  __shared__ float tmp[256];
  const int t = threadIdx.x;
  const long long off = (long long)blockIdx.x * D;
  float4 x4 = *reinterpret_cast<const float4*>(&x[off + t * 4]);
  tmp[t] = x4.x + x4.y + x4.z + x4.w;
  __syncthreads();
  for (int o = 128; o > 0; o >>= 1) { if (t < o) tmp[t] += tmp[t + o]; __syncthreads(); }
  const float mean = tmp[0] * (1.f / D);
  __syncthreads();
  float d0 = x4.x - mean, d1 = x4.y - mean, d2 = x4.z - mean, d3 = x4.w - mean;
  tmp[t] = d0 * d0 + d1 * d1 + d2 * d2 + d3 * d3;
  __syncthreads();
  for (int o = 128; o > 0; o >>= 1) { if (t < o) tmp[t] += tmp[t + o]; __syncthreads(); }
  const float rs = rsqrtf(tmp[0] * (1.f / D) + 1e-5f);
  float4 g4 = *reinterpret_cast<const float4*>(&g[t * 4]);
  float4 b4 = *reinterpret_cast<const float4*>(&bia[t * 4]);
  float o0 = (d0 * rs * g4.x + b4.x) * scale;
  float o1 = (d1 * rs * g4.y + b4.y) * scale;
  float o2 = (d2 * rs * g4.z + b4.z) * scale;
  float o3 = (d3 * rs * g4.w + b4.w) * scale;
  if (y) {
    float4 o4 = {o0, o1, o2, o3};
    *reinterpret_cast<float4*>(&y[off + t * 4]) = o4;
  }
  if (yb) {
    u16x4 ob = {f2b(o0), f2b(o1), f2b(o2), f2b(o3)};
    *reinterpret_cast<u16x4*>(&yb[off + t * 4]) = ob;
  }
}

// ---------------------------------------------------------------------------
__global__ __launch_bounds__(256)
void vox_softmax(float* __restrict__ s, const int* __restrict__ mask,
                 u16* __restrict__ wb)
{
  __shared__ float tmp[256];
  const int t = threadIdx.x;
  const int row = blockIdx.x, b = row / NQ;
  float* sr = s + (long long)row * NV;
  u16* wr = wb + (long long)row * NV;
  const int* mr = mask + b * NV;
  float vals[16];
  float lm = -INFINITY;
  #pragma unroll
  for (int j = 0; j < 16; ++j) {
    int n = t + j * 256;
    float x = mr[n] ? -INFINITY : sr[n];
    vals[j] = x;
    lm = fmaxf(lm, x);
  }
  tmp[t] = lm;
  __syncthreads();
  for (int o = 128; o > 0; o >>= 1) { if (t < o) tmp[t] = fmaxf(tmp[t], tmp[t + o]); __syncthreads(); }
  const float mx = tmp[0];
  __syncthreads();
  float ls = 0.f;
  #pragma unroll
  for (int j = 0; j < 16; ++j) { vals[j] = __expf(vals[j] - mx); ls += vals[j]; }
  tmp[t] = ls;
  __syncthreads();
  for (int o = 128; o > 0; o >>= 1) { if (t < o) tmp[t] += tmp[t + o]; __syncthreads(); }
  const float inv = 1.f / tmp[0];
  #pragma unroll
  for (int j = 0; j < 16; ++j) {
    float v = vals[j] * inv;
    sr[t + j * 256] = v;
    wr[t + j * 256] = f2b(v);
  }
}

__global__ __launch_bounds__(256)
void splitk_reduce(const float* __restrict__ part, float* __restrict__ out)
{
  const long long i = ((long long)blockIdx.x * 256 + threadIdx.x) * 4;
  const long long nd = (long long)NQ * D;
  const long long b = i / nd;
  const long long o = i - b * nd;
  const float* p = part + b * 4 * nd + o;
  float4 s0 = *reinterpret_cast<const float4*>(&p[0]);
  float4 s1 = *reinterpret_cast<const float4*>(&p[nd]);
  float4 s2 = *reinterpret_cast<const float4*>(&p[2 * nd]);
  float4 s3 = *reinterpret_cast<const float4*>(&p[3 * nd]);
  float4 r = {s0.x + s1.x + s2.x + s3.x, s0.y + s1.y + s2.y + s3.y,
              s0.z + s1.z + s2.z + s3.z, s0.w + s1.w + s2.w + s3.w};
  *reinterpret_cast<float4*>(&out[i]) = r;
}

// ---------------------------------------------------------------------------
extern "C" void kernel_launch(void* const* d_in, const int* in_sizes, int n_in,
                              void* d_out, int out_size, void* d_ws, size_t ws_size,
                              hipStream_t stream)
{
  const float* tgt   = (const float*)d_in[0];
  const float* mtxt  = (const float*)d_in[1];
  const float* vox   = (const float*)d_in[2];
  const float* qpos  = (const float*)d_in[3];
  const int*   mtx_m = (const int*)d_in[4];
  const int*   vox_m = (const int*)d_in[5];
  const float* Wq = (const float*)d_in[6];  const float* bq = (const float*)d_in[7];
  const float* Wk = (const float*)d_in[8];  const float* bk = (const float*)d_in[9];
  const float* Wv = (const float*)d_in[10]; const float* bv = (const float*)d_in[11];
  const float* Wo = (const float*)d_in[12]; const float* bo = (const float*)d_in[13];
  const float* W1 = (const float*)d_in[14]; const float* b1 = (const float*)d_in[15];
  const float* W2 = (const float*)d_in[16]; const float* b2 = (const float*)d_in[17];
  const float* ln1g = (const float*)d_in[18]; const float* ln1b = (const float*)d_in[19];
  const float* ln2g = (const float*)d_in[20]; const float* ln2b = (const float*)d_in[21];

  float* out0 = (float*)d_out;                       // attn_output  [B,NQ,D]
  float* out1 = out0 + (long long)B * NQ * D;        // txt_cross    [B,NQ,LT]
  float* out2 = out1 + (long long)B * NQ * LT;       // attn_weights [B,NQ,NV]

  char* base = (char*)d_ws;
  constexpr size_t MB = 1ull << 20;
  u16*   kvW   = (u16*)(base + 0 * MB);     // 16  [Wk;Wv] stacked
  u16*   Wq_b  = (u16*)(base + 16 * MB);    // 2
  u16*   Wo_b  = (u16*)(base + 18 * MB);    // 2
  u16*   W1_b  = (u16*)(base + 20 * MB);    // 4
  u16*   W2_b  = (u16*)(base + 24 * MB);    // 4
  u16*   tq_b  = (u16*)(base + 28 * MB);    // 4
  u16*   q_b   = (u16*)(base + 32 * MB);    // 4
  u16*   kv_b  = (u16*)(base + 36 * MB);    // 16  [B*LT][2048] (K half used)
  u16*   vT_b  = (u16*)(base + 52 * MB);    // 8   [B][D][LT]
  u16*   ctx_b = (u16*)(base + 60 * MB);    // 4
  float* x1p   = (float*)(base + 64 * MB);  // 8
  float* x1f   = (float*)(base + 72 * MB);  // 8
  u16*   x1_b  = (u16*)(base + 80 * MB);    // 4
  u16*   ff1_b = (u16*)(base + 84 * MB);    // 8
  float* x2p   = (float*)(base + 92 * MB);  // 8
  u16*   x2s_b = (u16*)(base + 100 * MB);   // 4
  u16*   mtxt_b = (u16*)(base + 104 * MB);  // 32  dead after kv256b
  u16*   w_b    = (u16*)(base + 200 * MB);  // 32  dead after head_mean
  u16*   vox_b  = (u16*)(base + 104 * MB);  // 64  overlays mtxt_b (dead)
  u16*   voxT_b = (u16*)(base + 168 * MB);  // 64  overlays w_b (dead after head_mean)
  u16*   wvox_b = (u16*)(base + 0 * MB);    // 16  overlays kvW (dead)
  float* part   = (float*)(base + 16 * MB); // 32  overlays Wq..q_b (dead)

  const dim3 blk(256);
  const long long nd = (long long)NQ * D;

  // 1) conversions: fused weights + memory_txt + (tgt+qpos)
  Cvt8 ca;
  for (int i = 0; i < 8; ++i) ca.s2[i] = nullptr;
  ca.s[0] = Wq;   ca.d[0] = Wq_b;
  ca.s[1] = Wk;   ca.d[1] = kvW;
  ca.s[2] = Wv;   ca.d[2] = kvW + (long long)D * FTXT;
  ca.s[3] = Wo;   ca.d[3] = Wo_b;
  ca.s[4] = W1;   ca.d[4] = W1_b;
  ca.s[5] = W2;   ca.d[5] = W2_b;
  ca.s[6] = mtxt; ca.d[6] = mtxt_b;
  ca.s[7] = tgt;  ca.s2[7] = qpos; ca.d[7] = tq_b;
  ca.cum[0] = 0;     ca.cum[1] = 1024;  ca.cum[2] = 5120;  ca.cum[3] = 9216;
  ca.cum[4] = 10240; ca.cum[5] = 12288; ca.cum[6] = 14336; ca.cum[7] = 30720;
  ca.cum[8] = 32768;
  cvt_multi<<<dim3(32768), blk, 0, stream>>>(ca);

  // 2) q projection (2-phase) + kv projection (merged-phase; V -> vT fused)
  gemm_bf16<64,64,2,2, E_BIAS|E_WB16><<<dim3(D/64, (B*NQ)/64, 1), blk, 0, stream>>>(
      tq_b, Wq_b, bq, nullptr, nullptr, q_b, D, D, D, D, 1, 0,0,0,0,0,0, 1.f);
  gemm_kv256b<<<dim3(16, 16), dim3(512), 0, stream>>>(mtxt_b, kvW, bk, bv, kv_b, vT_b);

  // 3) fused text attention (scores + softmax + P@V; w -> w_b)
  fused_txt_attn<<<dim3(2, H, B), dim3(512), 0, stream>>>(
      q_b, kv_b, vT_b, mtx_m, ctx_b, w_b);
  //    out1 = head mean of w_b
  head_mean<<<dim3((B * NQ * LT) / 512), blk, 0, stream>>>(w_b, out1);

  // 4) vox -> vox_b + voxT_b (one f32 read; w_b dead now)
  vox_prep<<<dim3(D/64, NV/64, B), blk, 0, stream>>>(vox, vox_b, voxT_b);

  // 5) x1p = tgt + ctx @ Wo^T + bo
  gemm_bf16<64,64,2,2, E_BIAS|E_RES|E_WF32><<<dim3(D/64, (B*NQ)/64, 1), blk, 0, stream>>>(
      ctx_b, Wo_b, bo, tgt, x1p, nullptr, D, D, D, D, 1, 0,0,0,0,0,0, 1.f);

  // 6) LN1
  ln_kernel<<<dim3(B*NQ), blk, 0, stream>>>(x1p, ln1g, ln1b, x1f, x1_b, 1.f);

  // 7) ff1 = relu(x1 @ W1^T + b1)
  gemm_bf16<128,64,2,2, E_BIAS|E_RELU|E_WB16><<<dim3(DFF/64, (B*NQ)/128, 1), blk, 0, stream>>>(
      x1_b, W1_b, b1, nullptr, nullptr, ff1_b, D, D, D, DFF, 1, 0,0,0,0,0,0, 1.f);

  // 8) x2p = x1 + ff1 @ W2^T + b2
  gemm_bf16<64,64,2,2, E_BIAS|E_RES|E_WF32><<<dim3(D/64, (B*NQ)/64, 1), blk, 0, stream>>>(
      ff1_b, W2_b, b2, x1f, x2p, nullptr, DFF, DFF, DFF, D, 1, 0,0,0,0,0,0, 1.f);

  // 9) LN2 -> x2s (bf16, /sqrt(D))
  ln_kernel<<<dim3(B*NQ), blk, 0, stream>>>(x2p, ln2g, ln2b, nullptr, x2s_b, 0.03125f);

  // 10) out2 = x2s @ vox_b^T  (merged-phase)
  gemm8<1><<<dim3(NV/128, 1, B), dim3(512), 0, stream>>>(
      x2s_b, vox_b, out2, D, D, D, NV, 0,
      nd, (long long)NV * D, (long long)NQ * NV, 0);

  // 11) masked softmax in place; bf16 weights
  vox_softmax<<<dim3(B*NQ), blk, 0, stream>>>(out2, vox_m, wvox_b);

  // 12) out0 partials: merged-phase split-K=4 + reduce
  gemm8<4><<<dim3(D/128, 1, B*4), dim3(512), 0, stream>>>(
      wvox_b, voxT_b, part, NV/4, NV, NV, D, NV/4,
      (long long)NQ * NV, (long long)D * NV, 4 * nd, nd);
  splitk_reduce<<<dim3((B * NQ * D) / 1024), blk, 0, stream>>>(part, out0);
}

// Round 19
// 369.661 us; speedup vs baseline: 1.1110x; 1.0012x over previous
//
#include <hip/hip_runtime.h>
#include <math.h>

typedef unsigned short u16;
typedef unsigned int u32;
typedef __bf16 bf16x8 __attribute__((ext_vector_type(8)));
typedef float f32x4 __attribute__((ext_vector_type(4)));
typedef u16 u16x4 __attribute__((ext_vector_type(4)));
typedef u16 u16x2 __attribute__((ext_vector_type(2)));

constexpr int B = 8, NQ = 256, LT = 512, NV = 4096;
constexpr int D = 1024, H = 16, DFF = 2048, FTXT = 4096, HD = 64;

__device__ __forceinline__ u16 f2b(float f) {
  u32 u = __builtin_bit_cast(u32, f);
  return (u16)((u + 0x7fffu + ((u >> 16) & 1u)) >> 16);   // RNE
}
__device__ __forceinline__ float b2f(u16 b) {
  u32 u = ((u32)b) << 16;
  return __builtin_bit_cast(float, u);
}
__device__ __forceinline__ void gload16(const void* g, void* l) {
  __builtin_amdgcn_global_load_lds(
      (const __attribute__((address_space(1))) u32*)g,
      (__attribute__((address_space(3))) u32*)l, 16, 0, 0);
}

// ===========================================================================
// Fused text attention (R18-verified): one block per (qhalf, h, b).
// ===========================================================================
__global__ __launch_bounds__(512, 1)
void fused_txt_attn(const u16* __restrict__ qb, const u16* __restrict__ kvb,
                    const u16* __restrict__ vT, const int* __restrict__ mask,
                    u16* __restrict__ ctx, u16* __restrict__ wout)
{
  __shared__ __align__(16) u16 lds[78848];   // 154 KB
  u16* Qs = lds;
  u16* Ks = lds + 8192;
  u16* Ps = lds;
  u16* Vs = lds + 65536;
  float* red = (float*)(lds + 77824);

  const int qhalf = blockIdx.x, h = blockIdx.y, b = blockIdx.z;
  const int t = threadIdx.x;
  const int w = t >> 6, l = t & 63;
  const int l15 = l & 15, l4 = l >> 4;
  const int wr64 = (w >> 2) * 64;
  const int wc128 = (w & 3) * 128;
  const int q0 = b * NQ + qhalf * 128;

  {
    const int srow = t >> 3;
    const int sch = (t & 7) ^ (srow & 7);
    #pragma unroll
    for (int i = 0; i < 2; ++i)
      gload16(&qb[(long long)(q0 + srow + 64 * i) * D + h * HD + sch * 8],
              &Qs[(srow + 64 * i) * 64]);
    #pragma unroll
    for (int i = 0; i < 8; ++i)
      gload16(&kvb[(long long)(b * LT + srow + 64 * i) * 2048 + h * HD + sch * 8],
              &Ks[(srow + 64 * i) * 64]);
  }
  asm volatile("s_waitcnt vmcnt(0)" ::: "memory");
  __syncthreads();

  f32x4 acc[4][8];
  {
    bf16x8 a_[4][2], b_[8][2];
    #pragma unroll
    for (int fm = 0; fm < 4; ++fm) {
      const int r = wr64 + fm * 16 + l15;
      a_[fm][0] = *reinterpret_cast<const bf16x8*>(&Qs[r * 64 + (((0 * 4 + l4) ^ (r & 7)) * 8)]);
      a_[fm][1] = *reinterpret_cast<const bf16x8*>(&Qs[r * 64 + (((1 * 4 + l4) ^ (r & 7)) * 8)]);
    }
    #pragma unroll
    for (int fn = 0; fn < 8; ++fn) {
      const int r = wc128 + fn * 16 + l15;
      b_[fn][0] = *reinterpret_cast<const bf16x8*>(&Ks[r * 64 + (((0 * 4 + l4) ^ (r & 7)) * 8)]);
      b_[fn][1] = *reinterpret_cast<const bf16x8*>(&Ks[r * 64 + (((1 * 4 + l4) ^ (r & 7)) * 8)]);
    }
    #pragma unroll
    for (int fm = 0; fm < 4; ++fm)
      #pragma unroll
      for (int fn = 0; fn < 8; ++fn) {
        f32x4 c = {0.f, 0.f, 0.f, 0.f};
        c = __builtin_amdgcn_mfma_f32_16x16x32_bf16(a_[fm][0], b_[fn][0], c, 0, 0, 0);
        c = __builtin_amdgcn_mfma_f32_16x16x32_bf16(a_[fm][1], b_[fn][1], c, 0, 0, 0);
        acc[fm][fn] = c;
      }
  }

  int mk[8];
  #pragma unroll
  for (int fn = 0; fn < 8; ++fn) mk[fn] = mask[b * LT + wc128 + fn * 16 + l15];
  #pragma unroll
  for (int fm = 0; fm < 4; ++fm)
    #pragma unroll
    for (int fn = 0; fn < 8; ++fn)
      #pragma unroll
      for (int r = 0; r < 4; ++r)
        acc[fm][fn][r] = mk[fn] ? -INFINITY : acc[fm][fn][r] * 0.125f;

  float mx[4][4];
  #pragma unroll
  for (int fm = 0; fm < 4; ++fm)
    #pragma unroll
    for (int r = 0; r < 4; ++r) {
      float m = acc[fm][0][r];
      #pragma unroll
      for (int fn = 1; fn < 8; ++fn) m = fmaxf(m, acc[fm][fn][r]);
      #pragma unroll
      for (int o = 1; o < 16; o <<= 1) m = fmaxf(m, __shfl_xor(m, o, 64));
      mx[fm][r] = m;
    }
  if (l15 == 0) {
    #pragma unroll
    for (int fm = 0; fm < 4; ++fm)
      #pragma unroll
      for (int r = 0; r < 4; ++r)
        red[(wr64 + fm * 16 + l4 * 4 + r) * 4 + (w & 3)] = mx[fm][r];
  }
  __syncthreads();
  #pragma unroll
  for (int fm = 0; fm < 4; ++fm)
    #pragma unroll
    for (int r = 0; r < 4; ++r) {
      const int row = wr64 + fm * 16 + l4 * 4 + r;
      mx[fm][r] = fmaxf(fmaxf(red[row * 4 + 0], red[row * 4 + 1]),
                        fmaxf(red[row * 4 + 2], red[row * 4 + 3]));
    }
  __syncthreads();

  float sm[4][4];
  #pragma unroll
  for (int fm = 0; fm < 4; ++fm)
    #pragma unroll
    for (int r = 0; r < 4; ++r) {
      float s = 0.f;
      #pragma unroll
      for (int fn = 0; fn < 8; ++fn) {
        float e = __expf(acc[fm][fn][r] - mx[fm][r]);
        acc[fm][fn][r] = e;
        s += e;
      }
      #pragma unroll
      for (int o = 1; o < 16; o <<= 1) s += __shfl_xor(s, o, 64);
      sm[fm][r] = s;
    }
  if (l15 == 0) {
    #pragma unroll
    for (int fm = 0; fm < 4; ++fm)
      #pragma unroll
      for (int r = 0; r < 4; ++r)
        red[(wr64 + fm * 16 + l4 * 4 + r) * 4 + (w & 3)] = sm[fm][r];
  }
  __syncthreads();
  #pragma unroll
  for (int fm = 0; fm < 4; ++fm)
    #pragma unroll
    for (int r = 0; r < 4; ++r) {
      const int row = wr64 + fm * 16 + l4 * 4 + r;
      sm[fm][r] = 1.f / (red[row * 4 + 0] + red[row * 4 + 1] +
                         red[row * 4 + 2] + red[row * 4 + 3]);
    }
  __syncthreads();

  #pragma unroll
  for (int fm = 0; fm < 4; ++fm)
    #pragma unroll
    for (int r = 0; r < 4; ++r) {
      const int row = wr64 + fm * 16 + l4 * 4 + r;
      #pragma unroll
      for (int fn = 0; fn < 8; ++fn) {
        const int col = wc128 + fn * 16 + l15;
        const float p = acc[fm][fn][r] * sm[fm][r];
        const int kt = col >> 6, c6 = col & 63;
        Ps[kt * 8192 + row * 64 + (((c6 >> 3) ^ (row & 7)) * 8) + (c6 & 7)] = f2b(p);
      }
    }
  __syncthreads();

  auto stV = [&](int slab, int kt) {
    const int srow = t >> 3;
    const int sch = (t & 7) ^ (srow & 7);
    gload16(&vT[((long long)b * D + h * HD + srow) * LT + kt * 64 + sch * 8],
            &Vs[slab * 4096 + srow * 64]);
  };
  stV(0, 0); stV(1, 1);

  {
    const long long wbase = (((long long)(b * H + h)) * NQ + qhalf * 128) * LT;
    #pragma unroll
    for (int j = 0; j < 16; ++j) {
      const int chunk = t + j * 512;
      const int kt = chunk >> 10;
      const int c = chunk & 1023;
      const int row = c >> 3;
      const int s = c & 7;
      bf16x8 v = *reinterpret_cast<const bf16x8*>(&Ps[kt * 8192 + row * 64 + s * 8]);
      const int g = s ^ (row & 7);
      *reinterpret_cast<bf16x8*>(&wout[wbase + (long long)row * LT + kt * 64 + g * 8]) = v;
    }
  }

  asm volatile("s_waitcnt vmcnt(1)" ::: "memory");
  __syncthreads();

  f32x4 acc2[4] = {};
  const int pvr = w * 16;
  int s0 = 0, s1 = 1, s2 = 2;
  for (int kt = 0; kt < 8; ++kt) {
    bf16x8 pa[2], vb[4][2];
    {
      const int r = pvr + l15;
      pa[0] = *reinterpret_cast<const bf16x8*>(&Ps[kt * 8192 + r * 64 + (((0 * 4 + l4) ^ (r & 7)) * 8)]);
      pa[1] = *reinterpret_cast<const bf16x8*>(&Ps[kt * 8192 + r * 64 + (((1 * 4 + l4) ^ (r & 7)) * 8)]);
      #pragma unroll
      for (int fn = 0; fn < 4; ++fn) {
        const int vr = fn * 16 + l15;
        vb[fn][0] = *reinterpret_cast<const bf16x8*>(&Vs[s0 * 4096 + vr * 64 + (((0 * 4 + l4) ^ (vr & 7)) * 8)]);
        vb[fn][1] = *reinterpret_cast<const bf16x8*>(&Vs[s0 * 4096 + vr * 64 + (((1 * 4 + l4) ^ (vr & 7)) * 8)]);
      }
    }
    if (kt < 6) stV(s2, kt + 2);
    #pragma unroll
    for (int fn = 0; fn < 4; ++fn) {
      acc2[fn] = __builtin_amdgcn_mfma_f32_16x16x32_bf16(pa[0], vb[fn][0], acc2[fn], 0, 0, 0);
      acc2[fn] = __builtin_amdgcn_mfma_f32_16x16x32_bf16(pa[1], vb[fn][1], acc2[fn], 0, 0, 0);
    }
    if (kt < 6)       { asm volatile("s_waitcnt vmcnt(1)" ::: "memory"); }
    else if (kt == 6) { asm volatile("s_waitcnt vmcnt(0)" ::: "memory"); }
    __syncthreads();
    const int tmp = s0; s0 = s1; s1 = s2; s2 = tmp;
  }

  #pragma unroll
  for (int fn = 0; fn < 4; ++fn)
    #pragma unroll
    for (int r = 0; r < 4; ++r) {
      const int row = pvr + l4 * 4 + r;
      ctx[(long long)(q0 + row) * D + h * HD + fn * 16 + l15] = f2b(acc2[fn][r]);
    }
}

// out1[b,q,l] = mean over h of w_bf[b,h,q,l]
__global__ __launch_bounds__(256)
void head_mean(const u16* __restrict__ w, float* __restrict__ out1)
{
  const long long idx = ((long long)blockIdx.x * 256 + threadIdx.x) * 2;
  const int b = (int)(idx >> 17);
  const long long ql = idx & 131071;
  const u16* p = w + ((long long)b * H) * 131072 + ql;
  float s0 = 0.f, s1 = 0.f;
  #pragma unroll
  for (int h = 0; h < H; ++h) {
    const u16x2 v = *reinterpret_cast<const u16x2*>(&p[(long long)h * 131072]);
    s0 += b2f(v[0]); s1 += b2f(v[1]);
  }
  float2 o = {s0 * (1.f / H), s1 * (1.f / H)};
  *reinterpret_cast<float2*>(&out1[idx]) = o;
}

// ===========================================================================
// Merged-phase 256x128 schedule (R13/R15-verified).
// ===========================================================================
__global__ __launch_bounds__(512, 2)
void gemm_kv256b(const u16* __restrict__ A, const u16* __restrict__ Bw,
                 const float* __restrict__ bk_, const float* __restrict__ bv_,
                 u16* __restrict__ Cb, u16* __restrict__ vT)
{
  __shared__ __align__(16) u16 As[3 * 16384];
  __shared__ __align__(16) u16 Bs[3 * 8192];

  const int gx = 16;
  const int flat = blockIdx.y * gx + blockIdx.x;
  const int qq = 256 >> 3;
  const int xcd = flat & 7, lid = flat >> 3;
  const int wg = xcd * qq + lid;
  const int bx = wg % gx;
  const int by = wg / gx;
  const int m0 = by * 256, n0 = bx * 128;
  const float* bias = (n0 < 1024) ? (bk_ + n0) : (bv_ + (n0 - 1024));

  const int t = threadIdx.x;
  const int w = t >> 6, l = t & 63;
  const int wr64 = (w >> 1) * 64;
  const int wc64 = (w & 1) * 64;
  const int l15 = l & 15, l4 = l >> 4, l7 = l & 7;

  auto stA = [&](int slab, int tile) {
    const long long kk = (long long)tile * 64 + (((t & 7) ^ ((t >> 3) & 7)) * 8);
    #pragma unroll
    for (int i = 0; i < 4; ++i)
      gload16(&A[(long long)(m0 + (t >> 3) + 64 * i) * 4096 + kk],
              &As[slab * 16384 + (w * 8 + 64 * i) * 64]);
  };
  auto stB = [&](int slab, int tile) {
    const long long kk = (long long)tile * 64 + (((t & 7) ^ ((t >> 3) & 7)) * 8);
    #pragma unroll
    for (int i = 0; i < 2; ++i)
      gload16(&Bw[(long long)(n0 + (t >> 3) + 64 * i) * 4096 + kk],
              &Bs[slab * 8192 + (w * 8 + 64 * i) * 64]);
  };

#define RDA(sl,fm,ks) \
  (*reinterpret_cast<const bf16x8*>(&As[(sl)*16384 + \
      (wr64 + (fm)*16 + l15)*64 + ((((ks)*4 + l4) ^ l7) * 8)]))
#define RDB(sl,fn,ks) \
  (*reinterpret_cast<const bf16x8*>(&Bs[(sl)*8192 + \
      (wc64 + (fn)*16 + l15)*64 + ((((ks)*4 + l4) ^ l7) * 8)]))

  f32x4 acc[4][4] = {};
  bf16x8 a_[4][2];
  bf16x8 b_[4][2];

#define BAR asm volatile("s_barrier" ::: "memory")
#define WAIT6 asm volatile("s_waitcnt vmcnt(6)" ::: "memory")
#define WAIT0 asm volatile("s_waitcnt vmcnt(0)" ::: "memory")

  stA(0, 0); stB(0, 0);
  stA(1, 1); stB(1, 1);
  WAIT6;
  BAR;

  int s0 = 0, s1 = 1, s2 = 2;
  for (int tt = 0; tt < 64; ++tt) {
    #pragma unroll
    for (int f = 0; f < 4; ++f) {
      a_[f][0] = RDA(s0, f, 0); a_[f][1] = RDA(s0, f, 1);
      b_[f][0] = RDB(s0, f, 0); b_[f][1] = RDB(s0, f, 1);
    }

    if (tt < 62) { stA(s2, tt + 2); stB(s2, tt + 2); }

    __builtin_amdgcn_s_setprio(1);
    #pragma unroll
    for (int fm = 0; fm < 4; ++fm)
      #pragma unroll
      for (int fn = 0; fn < 4; ++fn) {
        acc[fm][fn] = __builtin_amdgcn_mfma_f32_16x16x32_bf16(
            a_[fm][0], b_[fn][0], acc[fm][fn], 0, 0, 0);
        acc[fm][fn] = __builtin_amdgcn_mfma_f32_16x16x32_bf16(
            a_[fm][1], b_[fn][1], acc[fm][fn], 0, 0, 0);
      }
    __builtin_amdgcn_s_setprio(0);

    if (tt < 62)       { WAIT6; }
    else if (tt == 62) { WAIT0; }
    BAR;

    const int tmp = s0; s0 = s1; s1 = s2; s2 = tmp;
  }
#undef RDA
#undef RDB
#undef BAR
#undef WAIT6
#undef WAIT0

  if (n0 < 1024) {
    #pragma unroll
    for (int fm = 0; fm < 4; ++fm)
      #pragma unroll
      for (int r = 0; r < 4; ++r) {
        const long long row = m0 + wr64 + fm * 16 + l4 * 4 + r;
        #pragma unroll
        for (int fn = 0; fn < 4; ++fn) {
          const int lc = wc64 + fn * 16 + l15;
          Cb[row * 2048 + n0 + lc] = f2b(acc[fm][fn][r] + bias[lc]);
        }
      }
  } else {
    #pragma unroll
    for (int fm = 0; fm < 4; ++fm) {
      const int row0 = m0 + wr64 + fm * 16 + l4 * 4;
      const int bb = row0 >> 9;
      const int l0 = row0 & 511;
      #pragma unroll
      for (int fn = 0; fn < 4; ++fn) {
        const int lc = wc64 + fn * 16 + l15;
        const int d = n0 + lc - 1024;
        const float bi = bias[lc];
        u16x4 o = {f2b(acc[fm][fn][0] + bi), f2b(acc[fm][fn][1] + bi),
                   f2b(acc[fm][fn][2] + bi), f2b(acc[fm][fn][3] + bi)};
        *reinterpret_cast<u16x4*>(&vT[((long long)bb * D + d) * LT + l0]) = o;
      }
    }
  }
}

// --- Generalized merged-phase 256x128: batch + split-K; OUTF 0=f32, 1=bf16 ---
template<int NZ2, int OUTF>
__global__ __launch_bounds__(512, 2)
void gemm8(const u16* __restrict__ A, const u16* __restrict__ Bw,
           float* __restrict__ C, u16* __restrict__ C16,
           int Ksub, int lda, int ldb, int ldc, int kstep,
           long long sA1, long long sB1, long long sC1, long long sC2)
{
  __shared__ __align__(16) u16 As[3 * 16384];
  __shared__ __align__(16) u16 Bs[3 * 8192];

  const int gx = gridDim.x, gy = gridDim.y;
  const int nwg = gx * gy * gridDim.z;
  const int flat = (blockIdx.z * gy + blockIdx.y) * gx + blockIdx.x;
  const int qq = nwg >> 3, rr = nwg & 7;
  const int xcd = flat & 7, lid = flat >> 3;
  const int wg = (xcd < rr ? xcd * (qq + 1) : rr * (qq + 1) + (xcd - rr) * qq) + lid;
  const int bx = wg % gx;
  const int tmp1 = wg / gx;
  const int by = tmp1 % gy, bz = tmp1 / gy;
  const int z1 = bz / NZ2, z2 = bz % NZ2;
  const int m0 = by * 256, n0 = bx * 128;
  const long long kbase = (long long)z2 * kstep;
  const u16* Ab = A + (long long)z1 * sA1;
  const u16* Bb = Bw + (long long)z1 * sB1;
  const long long coff = (long long)z1 * sC1 + (long long)z2 * sC2;

  const int t = threadIdx.x;
  const int w = t >> 6, l = t & 63;
  const int wr64 = (w >> 1) * 64;
  const int wc64 = (w & 1) * 64;
  const int l15 = l & 15, l4 = l >> 4, l7 = l & 7;

  auto stA = [&](int slab, int tile) {
    const long long kk = kbase + (long long)tile * 64 + (((t & 7) ^ ((t >> 3) & 7)) * 8);
    #pragma unroll
    for (int i = 0; i < 4; ++i)
      gload16(&Ab[(long long)(m0 + (t >> 3) + 64 * i) * lda + kk],
              &As[slab * 16384 + (w * 8 + 64 * i) * 64]);
  };
  auto stB = [&](int slab, int tile) {
    const long long kk = kbase + (long long)tile * 64 + (((t & 7) ^ ((t >> 3) & 7)) * 8);
    #pragma unroll
    for (int i = 0; i < 2; ++i)
      gload16(&Bb[(long long)(n0 + (t >> 3) + 64 * i) * ldb + kk],
              &Bs[slab * 8192 + (w * 8 + 64 * i) * 64]);
  };

#define RDA(sl,fm,ks) \
  (*reinterpret_cast<const bf16x8*>(&As[(sl)*16384 + \
      (wr64 + (fm)*16 + l15)*64 + ((((ks)*4 + l4) ^ l7) * 8)]))
#define RDB(sl,fn,ks) \
  (*reinterpret_cast<const bf16x8*>(&Bs[(sl)*8192 + \
      (wc64 + (fn)*16 + l15)*64 + ((((ks)*4 + l4) ^ l7) * 8)]))

  f32x4 acc[4][4] = {};
  bf16x8 a_[4][2];
  bf16x8 b_[4][2];

#define BAR asm volatile("s_barrier" ::: "memory")
#define WAIT6 asm volatile("s_waitcnt vmcnt(6)" ::: "memory")
#define WAIT0 asm volatile("s_waitcnt vmcnt(0)" ::: "memory")

  stA(0, 0); stB(0, 0);
  stA(1, 1); stB(1, 1);
  WAIT6;
  BAR;

  const int nt = Ksub >> 6;
  int s0 = 0, s1 = 1, s2 = 2;
  for (int tt = 0; tt < nt; ++tt) {
    #pragma unroll
    for (int f = 0; f < 4; ++f) {
      a_[f][0] = RDA(s0, f, 0); a_[f][1] = RDA(s0, f, 1);
      b_[f][0] = RDB(s0, f, 0); b_[f][1] = RDB(s0, f, 1);
    }

    if (tt < nt - 2) { stA(s2, tt + 2); stB(s2, tt + 2); }

    __builtin_amdgcn_s_setprio(1);
    #pragma unroll
    for (int fm = 0; fm < 4; ++fm)
      #pragma unroll
      for (int fn = 0; fn < 4; ++fn) {
        acc[fm][fn] = __builtin_amdgcn_mfma_f32_16x16x32_bf16(
            a_[fm][0], b_[fn][0], acc[fm][fn], 0, 0, 0);
        acc[fm][fn] = __builtin_amdgcn_mfma_f32_16x16x32_bf16(
            a_[fm][1], b_[fn][1], acc[fm][fn], 0, 0, 0);
      }
    __builtin_amdgcn_s_setprio(0);

    if (tt < nt - 2)       { WAIT6; }
    else if (tt == nt - 2) { WAIT0; }
    BAR;

    const int tmp = s0; s0 = s1; s1 = s2; s2 = tmp;
  }
#undef RDA
#undef RDB
#undef BAR
#undef WAIT6
#undef WAIT0

  #pragma unroll
  for (int fm = 0; fm < 4; ++fm)
    #pragma unroll
    for (int r = 0; r < 4; ++r) {
      const long long row = m0 + wr64 + fm * 16 + l4 * 4 + r;
      #pragma unroll
      for (int fn = 0; fn < 4; ++fn) {
        const int lc = wc64 + fn * 16 + l15;
        if (OUTF == 0) C[coff + row * (long long)ldc + n0 + lc] = acc[fm][fn][r];
        else           C16[coff + row * (long long)ldc + n0 + lc] = f2b(acc[fm][fn][r]);
      }
    }
}

// ---------------------------------------------------------------------------
// 2-phase bf16 MFMA GEMM (bf16 B via global_load_lds only).
// ---------------------------------------------------------------------------
constexpr int E_BIAS = 1, E_RES = 2, E_RELU = 4, E_WF32 = 8, E_WB16 = 16;

template<int BM, int BN, int WM, int WN, int EPI>
__global__ __launch_bounds__(256)
void gemm_bf16(const u16* __restrict__ A, const u16* __restrict__ Bw,
               const float* __restrict__ bias, const float* __restrict__ res,
               float* __restrict__ C, u16* __restrict__ Cb,
               int K, int lda, int ldb, int ldc, int nbz2,
               long long sA1, long long sA2, long long sB1, long long sB2,
               long long sC1, long long sC2, float alpha)
{
  constexpr int SM = BM / WM, SN = BN / WN;
  constexpr int FM = SM / 16, FN = SN / 16;
  constexpr int PA = BM / 64, PB = BN / 64;
  __shared__ __align__(16) u16 As[2][BM * 32];
  __shared__ __align__(16) u16 Bs[2][BN * 32];

  const int gx = gridDim.x, gy = gridDim.y;
  const int nwg = gx * gy * gridDim.z;
  const int flat = (blockIdx.z * gy + blockIdx.y) * gx + blockIdx.x;
  const int qq = nwg >> 3, rr = nwg & 7;
  const int xcd = flat & 7, lid = flat >> 3;
  const int wg = (xcd < rr ? xcd * (qq + 1) : rr * (qq + 1) + (xcd - rr) * qq) + lid;
  const int bx = wg % gx;
  const int tmp1 = wg / gx;
  const int by = tmp1 % gy, bz = tmp1 / gy;

  const int t = threadIdx.x;
  const int w = t >> 6, l = t & 63;
  const int wr = w / WN, wc = w % WN;
  const int m0 = by * BM, n0 = bx * BN;
  const long long offA = (long long)(bz / nbz2) * sA1 + (long long)(bz % nbz2) * sA2;
  const long long offB = (long long)(bz / nbz2) * sB1 + (long long)(bz % nbz2) * sB2;
  const long long offC = (long long)(bz / nbz2) * sC1 + (long long)(bz % nbz2) * sC2;
  const u16* Ab = A + offA;
  const u16* Bb = Bw + offB;

  const int srow = t >> 2;
  const int sk   = (t & 3) * 8;

  auto stageA = [&](int buf, int k0) {
    #pragma unroll
    for (int p = 0; p < PA; ++p)
      gload16(&Ab[(long long)(m0 + p * 64 + srow) * lda + k0 + sk],
              &As[buf][p * 2048 + w * 512]);
  };
  auto stageB = [&](int buf, int k0) {
    #pragma unroll
    for (int p = 0; p < PB; ++p)
      gload16(&Bb[(long long)(n0 + p * 64 + srow) * ldb + k0 + sk],
              &Bs[buf][p * 2048 + w * 512]);
  };

  f32x4 acc[FM][FN] = {};

  stageA(0, 0);
  stageB(0, 0);

  int cur = 0;
  for (int k0 = 0; k0 < K; k0 += 32) {
    __syncthreads();
    const bool pf = (k0 + 32 < K);
    if (pf) {
      stageA(cur ^ 1, k0 + 32);
      stageB(cur ^ 1, k0 + 32);
    }

    bf16x8 af[FM], bfr[FN];
    #pragma unroll
    for (int i = 0; i < FM; ++i)
      af[i] = *reinterpret_cast<const bf16x8*>(
          &As[cur][(wr * SM + i * 16 + (l & 15)) * 32 + (l >> 4) * 8]);
    #pragma unroll
    for (int j = 0; j < FN; ++j)
      bfr[j] = *reinterpret_cast<const bf16x8*>(
          &Bs[cur][(wc * SN + j * 16 + (l & 15)) * 32 + (l >> 4) * 8]);
    #pragma unroll
    for (int i = 0; i < FM; ++i)
      #pragma unroll
      for (int j = 0; j < FN; ++j)
        acc[i][j] = __builtin_amdgcn_mfma_f32_16x16x32_bf16(af[i], bfr[j], acc[i][j], 0, 0, 0);
    cur ^= 1;
  }

  const int c_l = l & 15, r_l4 = (l >> 4) * 4;
  #pragma unroll
  for (int i = 0; i < FM; ++i) {
    #pragma unroll
    for (int r = 0; r < 4; ++r) {
      const long long row = m0 + wr * SM + i * 16 + r_l4 + r;
      #pragma unroll
      for (int j = 0; j < FN; ++j) {
        const int col = n0 + wc * SN + j * 16 + c_l;
        float v = acc[i][j][r] * alpha;
        if (EPI & E_BIAS) v += bias[col];
        if (EPI & E_RES)  v += res[row * (long long)ldc + col];
        if (EPI & E_RELU) v = fmaxf(v, 0.f);
        const long long co = offC + row * (long long)ldc + col;
        if (EPI & E_WF32) C[co] = v;
        if (EPI & E_WB16) Cb[co] = f2b(v);
      }
    }
  }
}

// ---------------------------------------------------------------------------
__global__ __launch_bounds__(256)
void vox_prep(const float* __restrict__ in, u16* __restrict__ vb,
              u16* __restrict__ vt)
{
  __shared__ u16 tile[64][68];
  const int b = blockIdx.z;
  const int n0 = blockIdx.y * 64;
  const int d0 = blockIdx.x * 64;
  const int t = threadIdx.x;
  const int tr = t >> 4;
  const int tc = (t & 15) * 4;
  const float* ib = in + (long long)b * NV * D;
  u16* vbb = vb + (long long)b * NV * D;
  u16* vtb = vt + (long long)b * NV * D;
  #pragma unroll
  for (int p = 0; p < 4; ++p) {
    int r = tr + p * 16;
    float4 x = *reinterpret_cast<const float4*>(&ib[(long long)(n0 + r) * D + d0 + tc]);
    u16x4 o = {f2b(x.x), f2b(x.y), f2b(x.z), f2b(x.w)};
    *reinterpret_cast<u16x4*>(&vbb[(long long)(n0 + r) * D + d0 + tc]) = o;
    *reinterpret_cast<u16x4*>(&tile[r][tc]) = o;
  }
  __syncthreads();
  #pragma unroll
  for (int p = 0; p < 4; ++p) {
    int c = tr + p * 16;
    u16x4 o = {tile[tc + 0][c], tile[tc + 1][c], tile[tc + 2][c], tile[tc + 3][c]};
    *reinterpret_cast<u16x4*>(&vtb[(long long)(d0 + c) * NV + n0 + tc]) = o;
  }
}

// ---------------------------------------------------------------------------
struct Cvt8 { const float* s[8]; const float* s2[8]; u16* d[8]; int cum[9]; };

__global__ __launch_bounds__(256)
void cvt_multi(Cvt8 a)
{
  const int bidx = blockIdx.x;
  int seg = 0;
  #pragma unroll
  for (int k = 1; k < 8; ++k) if (bidx >= a.cum[k]) seg = k;
  const long long off = ((long long)(bidx - a.cum[seg]) * 256 + threadIdx.x) * 4;
  float4 x = *reinterpret_cast<const float4*>(a.s[seg] + off);
  if (a.s2[seg]) {
    float4 y = *reinterpret_cast<const float4*>(a.s2[seg] + off);
    x.x += y.x; x.y += y.y; x.z += y.z; x.w += y.w;
  }
  u16x4 o = {f2b(x.x), f2b(x.y), f2b(x.z), f2b(x.w)};
  *reinterpret_cast<u16x4*>(a.d[seg] + off) = o;
}

// ---------------------------------------------------------------------------
__global__ __launch_bounds__(256)
void ln_kernel(const float* __restrict__ x, const float* __restrict__ g,
               const float* __restrict__ bia, float* __restrict__ y,
               u16* __restrict__ yb, float scale)
{
  __shared__ float tmp[256];
  const int t = threadIdx.x;
  const long long off = (long long)blockIdx.x * D;
  float4 x4 = *reinterpret_cast<const float4*>(&x[off + t * 4]);
  tmp[t] = x4.x + x4.y + x4.z + x4.w;
  __syncthreads();
  for (int o = 128; o > 0; o >>= 1) { if (t < o) tmp[t] += tmp[t + o]; __syncthreads(); }
  const float mean = tmp[0] * (1.f / D);
  __syncthreads();
  float d0 = x4.x - mean, d1 = x4.y - mean, d2 = x4.z - mean, d3 = x4.w - mean;
  tmp[t] = d0 * d0 + d1 * d1 + d2 * d2 + d3 * d3;
  __syncthreads();
  for (int o = 128; o > 0; o >>= 1) { if (t < o) tmp[t] += tmp[t + o]; __syncthreads(); }
  const float rs = rsqrtf(tmp[0] * (1.f / D) + 1e-5f);
  float4 g4 = *reinterpret_cast<const float4*>(&g[t * 4]);
  float4 b4 = *reinterpret_cast<const float4*>(&bia[t * 4]);
  float o0 = (d0 * rs * g4.x + b4.x) * scale;
  float o1 = (d1 * rs * g4.y + b4.y) * scale;
  float o2 = (d2 * rs * g4.z + b4.z) * scale;
  float o3 = (d3 * rs * g4.w + b4.w) * scale;
  if (y) {
    float4 o4 = {o0, o1, o2, o3};
    *reinterpret_cast<float4*>(&y[off + t * 4]) = o4;
  }
  if (yb) {
    u16x4 ob = {f2b(o0), f2b(o1), f2b(o2), f2b(o3)};
    *reinterpret_cast<u16x4*>(&yb[off + t * 4]) = ob;
  }
}

// ---------------------------------------------------------------------------
// Masked softmax over rows of NV=4096: bf16 raw scores in -> f32 weights to
// out2 + bf16 weights to wb.
// ---------------------------------------------------------------------------
__global__ __launch_bounds__(256)
void vox_softmax(const u16* __restrict__ sc, const int* __restrict__ mask,
                 float* __restrict__ out2, u16* __restrict__ wb)
{
  __shared__ float tmp[256];
  const int t = threadIdx.x;
  const int row = blockIdx.x, b = row / NQ;
  const u16* sr = sc + (long long)row * NV;
  float* orow = out2 + (long long)row * NV;
  u16* wr = wb + (long long)row * NV;
  const int* mr = mask + b * NV;
  float vals[16];
  float lm = -INFINITY;
  #pragma unroll
  for (int j = 0; j < 16; ++j) {
    int n = t + j * 256;
    float x = mr[n] ? -INFINITY : b2f(sr[n]);
    vals[j] = x;
    lm = fmaxf(lm, x);
  }
  tmp[t] = lm;
  __syncthreads();
  for (int o = 128; o > 0; o >>= 1) { if (t < o) tmp[t] = fmaxf(tmp[t], tmp[t + o]); __syncthreads(); }
  const float mx = tmp[0];
  __syncthreads();
  float ls = 0.f;
  #pragma unroll
  for (int j = 0; j < 16; ++j) { vals[j] = __expf(vals[j] - mx); ls += vals[j]; }
  tmp[t] = ls;
  __syncthreads();
  for (int o = 128; o > 0; o >>= 1) { if (t < o) tmp[t] += tmp[t + o]; __syncthreads(); }
  const float inv = 1.f / tmp[0];
  #pragma unroll
  for (int j = 0; j < 16; ++j) {
    float v = vals[j] * inv;
    orow[t + j * 256] = v;
    wr[t + j * 256] = f2b(v);
  }
}

__global__ __launch_bounds__(256)
void splitk_reduce(const float* __restrict__ part, float* __restrict__ out)
{
  const long long i = ((long long)blockIdx.x * 256 + threadIdx.x) * 4;
  const long long nd = (long long)NQ * D;
  const long long b = i / nd;
  const long long o = i - b * nd;
  const float* p = part + b * 4 * nd + o;
  float4 s0 = *reinterpret_cast<const float4*>(&p[0]);
  float4 s1 = *reinterpret_cast<const float4*>(&p[nd]);
  float4 s2 = *reinterpret_cast<const float4*>(&p[2 * nd]);
  float4 s3 = *reinterpret_cast<const float4*>(&p[3 * nd]);
  float4 r = {s0.x + s1.x + s2.x + s3.x, s0.y + s1.y + s2.y + s3.y,
              s0.z + s1.z + s2.z + s3.z, s0.w + s1.w + s2.w + s3.w};
  *reinterpret_cast<float4*>(&out[i]) = r;
}

// ---------------------------------------------------------------------------
extern "C" void kernel_launch(void* const* d_in, const int* in_sizes, int n_in,
                              void* d_out, int out_size, void* d_ws, size_t ws_size,
                              hipStream_t stream)
{
  const float* tgt   = (const float*)d_in[0];
  const float* mtxt  = (const float*)d_in[1];
  const float* vox   = (const float*)d_in[2];
  const float* qpos  = (const float*)d_in[3];
  const int*   mtx_m = (const int*)d_in[4];
  const int*   vox_m = (const int*)d_in[5];
  const float* Wq = (const float*)d_in[6];  const float* bq = (const float*)d_in[7];
  const float* Wk = (const float*)d_in[8];  const float* bk = (const float*)d_in[9];
  const float* Wv = (const float*)d_in[10]; const float* bv = (const float*)d_in[11];
  const float* Wo = (const float*)d_in[12]; const float* bo = (const float*)d_in[13];
  const float* W1 = (const float*)d_in[14]; const float* b1 = (const float*)d_in[15];
  const float* W2 = (const float*)d_in[16]; const float* b2 = (const float*)d_in[17];
  const float* ln1g = (const float*)d_in[18]; const float* ln1b = (const float*)d_in[19];
  const float* ln2g = (const float*)d_in[20]; const float* ln2b = (const float*)d_in[21];

  float* out0 = (float*)d_out;                       // attn_output  [B,NQ,D]
  float* out1 = out0 + (long long)B * NQ * D;        // txt_cross    [B,NQ,LT]
  float* out2 = out1 + (long long)B * NQ * LT;       // attn_weights [B,NQ,NV]

  char* base = (char*)d_ws;
  constexpr size_t MB = 1ull << 20;
  u16*   kvW   = (u16*)(base + 0 * MB);     // 16  [Wk;Wv] stacked
  u16*   Wq_b  = (u16*)(base + 16 * MB);    // 2
  u16*   Wo_b  = (u16*)(base + 18 * MB);    // 2
  u16*   W1_b  = (u16*)(base + 20 * MB);    // 4
  u16*   W2_b  = (u16*)(base + 24 * MB);    // 4
  u16*   tq_b  = (u16*)(base + 28 * MB);    // 4
  u16*   q_b   = (u16*)(base + 32 * MB);    // 4
  u16*   kv_b  = (u16*)(base + 36 * MB);    // 16  [B*LT][2048] (dead after attn)
  u16*   vox_sc = (u16*)(base + 36 * MB);   // 16  bf16 vox scores (overlays kv_b)
  u16*   vT_b  = (u16*)(base + 52 * MB);    // 8   [B][D][LT]
  u16*   ctx_b = (u16*)(base + 60 * MB);    // 4
  float* x1p   = (float*)(base + 64 * MB);  // 8
  float* x1f   = (float*)(base + 72 * MB);  // 8
  u16*   x1_b  = (u16*)(base + 80 * MB);    // 4
  u16*   ff1_b = (u16*)(base + 84 * MB);    // 8
  float* x2p   = (float*)(base + 92 * MB);  // 8
  u16*   x2s_b = (u16*)(base + 100 * MB);   // 4
  u16*   mtxt_b = (u16*)(base + 104 * MB);  // 32  dead after kv256b
  u16*   w_b    = (u16*)(base + 200 * MB);  // 32  dead after head_mean
  u16*   vox_b  = (u16*)(base + 104 * MB);  // 64  overlays mtxt_b (dead)
  u16*   voxT_b = (u16*)(base + 168 * MB);  // 64  overlays w_b (dead after head_mean)
  u16*   wvox_b = (u16*)(base + 0 * MB);    // 16  overlays kvW (dead)
  float* part   = (float*)(base + 16 * MB); // 32  overlays Wq..q_b (dead)

  const dim3 blk(256);
  const long long nd = (long long)NQ * D;

  // 1) conversions: fused weights + memory_txt + (tgt+qpos)
  Cvt8 ca;
  for (int i = 0; i < 8; ++i) ca.s2[i] = nullptr;
  ca.s[0] = Wq;   ca.d[0] = Wq_b;
  ca.s[1] = Wk;   ca.d[1] = kvW;
  ca.s[2] = Wv;   ca.d[2] = kvW + (long long)D * FTXT;
  ca.s[3] = Wo;   ca.d[3] = Wo_b;
  ca.s[4] = W1;   ca.d[4] = W1_b;
  ca.s[5] = W2;   ca.d[5] = W2_b;
  ca.s[6] = mtxt; ca.d[6] = mtxt_b;
  ca.s[7] = tgt;  ca.s2[7] = qpos; ca.d[7] = tq_b;
  ca.cum[0] = 0;     ca.cum[1] = 1024;  ca.cum[2] = 5120;  ca.cum[3] = 9216;
  ca.cum[4] = 10240; ca.cum[5] = 12288; ca.cum[6] = 14336; ca.cum[7] = 30720;
  ca.cum[8] = 32768;
  cvt_multi<<<dim3(32768), blk, 0, stream>>>(ca);

  // 2) q projection (2-phase) + kv projection (merged-phase; V -> vT fused)
  gemm_bf16<64,64,2,2, E_BIAS|E_WB16><<<dim3(D/64, (B*NQ)/64, 1), blk, 0, stream>>>(
      tq_b, Wq_b, bq, nullptr, nullptr, q_b, D, D, D, D, 1, 0,0,0,0,0,0, 1.f);
  gemm_kv256b<<<dim3(16, 16), dim3(512), 0, stream>>>(mtxt_b, kvW, bk, bv, kv_b, vT_b);

  // 3) fused text attention (scores + softmax + P@V; w -> w_b)
  fused_txt_attn<<<dim3(2, H, B), dim3(512), 0, stream>>>(
      q_b, kv_b, vT_b, mtx_m, ctx_b, w_b);
  head_mean<<<dim3((B * NQ * LT) / 512), blk, 0, stream>>>(w_b, out1);

  // 4) vox -> vox_b + voxT_b (one f32 read; w_b dead now)
  vox_prep<<<dim3(D/64, NV/64, B), blk, 0, stream>>>(vox, vox_b, voxT_b);

  // 5) x1p = tgt + ctx @ Wo^T + bo
  gemm_bf16<64,64,2,2, E_BIAS|E_RES|E_WF32><<<dim3(D/64, (B*NQ)/64, 1), blk, 0, stream>>>(
      ctx_b, Wo_b, bo, tgt, x1p, nullptr, D, D, D, D, 1, 0,0,0,0,0,0, 1.f);

  // 6) LN1
  ln_kernel<<<dim3(B*NQ), blk, 0, stream>>>(x1p, ln1g, ln1b, x1f, x1_b, 1.f);

  // 7) ff1 = relu(x1 @ W1^T + b1)
  gemm_bf16<128,64,2,2, E_BIAS|E_RELU|E_WB16><<<dim3(DFF/64, (B*NQ)/128, 1), blk, 0, stream>>>(
      x1_b, W1_b, b1, nullptr, nullptr, ff1_b, D, D, D, DFF, 1, 0,0,0,0,0,0, 1.f);

  // 8) x2p = x1 + ff1 @ W2^T + b2
  gemm_bf16<64,64,2,2, E_BIAS|E_RES|E_WF32><<<dim3(D/64, (B*NQ)/64, 1), blk, 0, stream>>>(
      ff1_b, W2_b, b2, x1f, x2p, nullptr, DFF, DFF, DFF, D, 1, 0,0,0,0,0,0, 1.f);

  // 9) LN2 -> x2s (bf16, /sqrt(D))
  ln_kernel<<<dim3(B*NQ), blk, 0, stream>>>(x2p, ln2g, ln2b, nullptr, x2s_b, 0.03125f);

  // 10) vox raw scores = x2s @ vox_b^T  (merged-phase, bf16 out; kv_b dead)
  gemm8<1,1><<<dim3(NV/128, 1, B), dim3(512), 0, stream>>>(
      x2s_b, vox_b, nullptr, vox_sc, D, D, D, NV, 0,
      nd, (long long)NV * D, (long long)NQ * NV, 0);

  // 11) masked softmax: bf16 scores -> f32 out2 + bf16 weights
  vox_softmax<<<dim3(B*NQ), blk, 0, stream>>>(vox_sc, vox_m, out2, wvox_b);

  // 12) out0 partials: merged-phase split-K=4 + reduce
  gemm8<4,0><<<dim3(D/128, 1, B*4), dim3(512), 0, stream>>>(
      wvox_b, voxT_b, part, nullptr, NV/4, NV, NV, D, NV/4,
      (long long)NQ * NV, (long long)D * NV, 4 * nd, nd);
  splitk_reduce<<<dim3((B * NQ * D) / 1024), blk, 0, stream>>>(part, out0);
}